// Round 4
// baseline (407.360 us; speedup 1.0000x reference)
//
#include <hip/hip_runtime.h>
#include <stdint.h>

typedef __bf16 bf16x8 __attribute__((ext_vector_type(8)));
typedef float f32x4 __attribute__((ext_vector_type(4)));

// ---- workspace byte offsets ----
#define OFF_GWT   62914560u    // (g*W)^T bf16 per level [512][C]
#define OFF_H     66846720u    // h bf16 per level [8192][512]
#define OFF_U     100679680u   // 4*512 f32 (zeroed, atomic-accumulated)
#define OFF_GG    100687872u
#define OFF_BB    100696064u
#define OFF_SCAL  100704256u   // [0..3] sproto, [4..7] sqproto (zeroed)
#define WS_TOTAL  100719872u

__host__ __device__ __forceinline__ size_t gwt_off(int l) {
  return (size_t)262144u * (size_t)((1u << l) - 1u);
}

__device__ __forceinline__ unsigned short f2bf(float x) {
  return (unsigned short)((__float_as_uint(x) + 0x8000u) >> 16);
}
__device__ __forceinline__ unsigned pack2(float a, float b) {
  return ((__float_as_uint(a) + 0x8000u) >> 16) |
         ((__float_as_uint(b) + 0x8000u) & 0xffff0000u);
}
__device__ __forceinline__ void async_load16(const void* g, void* l) {
  __builtin_amdgcn_global_load_lds((const __attribute__((address_space(1))) void*)g,
                                   (__attribute__((address_space(3))) void*)l,
                                   16, 0, 0);
}

struct PrepArgs {
  const float* pooled[4];
  const float* proto[4];
  const float* W[4];
  const float* g[4];
  const float* beta[4];
  const float* bias[4];
  const float* text;
  const float* lsc;
  char* ws;
};

// ================= wtrans: W-slab transpose + Gsum/Bsum/u + pmean/scal =================
// (unchanged this round — control kernel)
__global__ __launch_bounds__(256) void wtrans(PrepArgs A) {
  __shared__ unsigned short tile[128][66];     // padded: 2-way-only banking
  __shared__ float redG[4][128], redB[4][128], redU[4][128];
  __shared__ float gsh[64], bsh[64], psh[64];
  __shared__ float redP[4][64];
  int t = threadIdx.x, bid = blockIdx.x;
  int l, idl;
  if (bid < 256)      { l = 3; idl = bid; }
  else if (bid < 384) { l = 2; idl = bid - 256; }
  else if (bid < 448) { l = 1; idl = bid - 384; }
  else                { l = 0; idl = bid - 448; }
  int C = 256 << l;
  int sid = idl >> 2, dchunk = idl & 3;
  int j0 = sid * 64, d0 = dchunk * 128;
  bool top = (j0 < C);
  int w = t >> 6, L = t & 63;
  float* scal = (float*)(A.ws + OFF_SCAL);

  if (t < 64) {
    gsh[t] = A.g[l][j0 + t];
    bsh[t] = A.beta[l][j0 + t];
  }
  if (!top) {
    const float* pr = A.proto[l];
    int cb0 = j0 - C;
    float s = 0.f;
#pragma unroll
    for (int r = 0; r < 16; ++r) s += pr[(size_t)(w * 16 + r) * C + cb0 + L];
    redP[w][L] = s;
  }
  __syncthreads();
  if (!top) {
    if (t < 64) {
      float pmv = (redP[0][t] + redP[1][t] + redP[2][t] + redP[3][t]) * (1.0f / 64.0f);
      psh[t] = pmv * gsh[t];
      if (dchunk == 0) {
        float s1 = pmv, s2 = pmv * pmv;
#pragma unroll
        for (int off = 1; off < 64; off <<= 1) {
          s1 += __shfl_xor(s1, off);
          s2 += __shfl_xor(s2, off);
        }
        if (t == 0) {
          atomicAdd(&scal[l], s1);
          atomicAdd(&scal[4 + l], s2);
        }
      }
    }
    __syncthreads();
  }

  const float* W = A.W[l];
  float2 v[16];
#pragma unroll
  for (int r = 0; r < 16; ++r) {
    int j = j0 + w * 16 + r;
    v[r] = *(const float2*)(W + (size_t)j * 512 + d0 + 2 * L);
  }
  float gp0 = 0.f, gp1 = 0.f, bp0 = 0.f, bp1 = 0.f, up0 = 0.f, up1 = 0.f;
#pragma unroll
  for (int r = 0; r < 16; ++r) {
    int jl = w * 16 + r;
    float g = gsh[jl], b = bsh[jl];
    gp0 = fmaf(g, v[r].x, gp0); gp1 = fmaf(g, v[r].y, gp1);
    bp0 = fmaf(b, v[r].x, bp0); bp1 = fmaf(b, v[r].y, bp1);
    if (top) {
      tile[2 * L][jl] = f2bf(g * v[r].x);
      tile[2 * L + 1][jl] = f2bf(g * v[r].y);
    } else {
      float p = psh[jl];
      up0 = fmaf(p, v[r].x, up0); up1 = fmaf(p, v[r].y, up1);
    }
  }
  redG[w][2 * L] = gp0; redG[w][2 * L + 1] = gp1;
  redB[w][2 * L] = bp0; redB[w][2 * L + 1] = bp1;
  if (!top) { redU[w][2 * L] = up0; redU[w][2 * L + 1] = up1; }
  __syncthreads();

  if (t < 128) {
    int d = l * 512 + d0 + t;
    float G = redG[0][t] + redG[1][t] + redG[2][t] + redG[3][t];
    float B = redB[0][t] + redB[1][t] + redB[2][t] + redB[3][t];
    atomicAdd(&((float*)(A.ws + OFF_GG))[d], G);
    atomicAdd(&((float*)(A.ws + OFF_BB))[d], B);
    if (!top) {
      float U = redU[0][t] + redU[1][t] + redU[2][t] + redU[3][t];
      atomicAdd(&((float*)(A.ws + OFF_U))[d], U);
    }
  }
  if (top) {
    unsigned short* gwT = (unsigned short*)(A.ws + OFF_GWT + gwt_off(l));
    int d = t >> 1, jh = (t & 1) * 32;
    const unsigned* trow = (const unsigned*)&tile[d][jh];  // 4B-aligned
    uint4 q0 = make_uint4(trow[0], trow[1], trow[2], trow[3]);
    uint4 q1 = make_uint4(trow[4], trow[5], trow[6], trow[7]);
    uint4 q2 = make_uint4(trow[8], trow[9], trow[10], trow[11]);
    uint4 q3 = make_uint4(trow[12], trow[13], trow[14], trow[15]);
    uint4* dst = (uint4*)(gwT + (size_t)(d0 + d) * C + j0 + jh);
    dst[0] = q0; dst[1] = q1; dst[2] = q2; dst[3] = q3;
  }
}

// ================= gemm2: fused convert+GEMM, dbuf single-barrier pipeline =================
// XCD-chunk swizzle: bid -> (bid&7)*128 + (bid>>3). Each XCD owns a contiguous
// 128-block chunk (32 rb x 4 cb of one level): the 4 cb-siblings of an rb run
// concurrently on the same XCD -> A panel (<=1MB) and the level's 4 B panels
// (<=2MB) stay L2-resident.
// Pipeline per k-step (ONE barrier): issue B-DMA(k+1)->buf[nxt]; pack+ds_write
// A(k+1)->buf[nxt] (+row stats); issue A f32 loads(k+2); ds_read+MFMA buf[cur];
// __syncthreads (drains DMA, publishes ds_writes).
// LDS swizzle: granule s of row r holds k-granule s^((r>>1)&3). A: swizzled
// ds_write addr-free (source-side). B: DMA dest is linear (wave-uniform+lane*16),
// so the SOURCE address is pre-swizzled; reads use the matching XOR.
struct G2Args {
  char* ws;
  const float* pooled[4];
  const float* bias[4];
};

__global__ __launch_bounds__(256, 3) void gemm2(G2Args A) {
  __shared__ __align__(16) char lds[35328];   // A dbuf 16K | B dbuf 16K | misc 2.5K
  char* ws = A.ws;
  int t = threadIdx.x;
  int bid = ((blockIdx.x & 7) << 7) + (blockIdx.x >> 3);   // XCD chunking
  int l = 3 - (bid >> 8);
  int rb = (bid >> 2) & 63, cb = bid & 3;
  int C = 256 << l;
  int nst = C >> 5;
  int m0 = rb * 128, n0 = cb * 128;

  float* uArr  = (float*)(lds + 32768);
  float* gArr  = (float*)(lds + 33280);
  float* bArr  = (float*)(lds + 33792);
  float* rowM  = (float*)(lds + 34304);
  float* rowIS = (float*)(lds + 34816);
  const float* scal = (const float*)(ws + OFF_SCAL);

  if (t < 128) {
    int idx = l * 512 + n0 + t;
    uArr[t] = ((const float*)(ws + OFF_U))[idx];
    gArr[t] = ((const float*)(ws + OFF_GG))[idx];
    bArr[t] = ((const float*)(ws + OFF_BB))[idx] + A.bias[l][n0 + t];
  }

  int w = t >> 6, lane = t & 63, quad = lane >> 4, lc = lane & 15;

  // ---- B staging (DMA, source-swizzled) ----
  const char* Bw = ws + OFF_GWT + gwt_off(l);
  const char* bP[2];
#pragma unroll
  for (int i = 0; i < 2; ++i) {
    int li = i * 256 + t;
    int rr = li >> 2, s = li & 3;
    int kq = s ^ ((rr >> 1) & 3);
    bP[i] = Bw + ((size_t)(n0 + rr) * C + kq * 8) * 2;
  }
  char* BD = lds + 16384 + w * 1024;   // + buf*8192 (+4096 for i=1); lane*16 implicit

  // ---- A staging (reg pack, source-swizzled) ----
  int rA = t >> 2, sA = t & 3;
  int kqA = sA ^ ((rA >> 1) & 3);
  const float* aG0 = A.pooled[l] + (size_t)(m0 + rA) * C + kqA * 8;
  const float* aG1 = aG0 + (size_t)64 * C;
  int aOff0 = rA * 64 + sA * 16;       // + buf*8192
  int aOff1 = aOff0 + 4096;

  // ---- fragment read offsets (XOR matches the staging swizzle) ----
  int wr = (w >> 1) * 64, wc = (w & 1) * 64;
  int aFoff = (wr + lc) * 64 + (quad ^ (((wr + lc) >> 1) & 3)) * 16;
  int bFoff = (wc + lc) * 64 + (quad ^ (((wc + lc) >> 1) & 3)) * 16;

  f32x4 a0, a1, a2, a3;
  float s1a = 0.f, s2a = 0.f, s1b = 0.f, s2b = 0.f;
  auto packA = [&](int buf) {
    *(uint4*)(lds + buf * 8192 + aOff0) =
        make_uint4(pack2(a0[0], a0[1]), pack2(a0[2], a0[3]),
                   pack2(a1[0], a1[1]), pack2(a1[2], a1[3]));
    *(uint4*)(lds + buf * 8192 + aOff1) =
        make_uint4(pack2(a2[0], a2[1]), pack2(a2[2], a2[3]),
                   pack2(a3[0], a3[1]), pack2(a3[2], a3[3]));
    s1a += ((a0[0] + a0[1]) + (a0[2] + a0[3])) + ((a1[0] + a1[1]) + (a1[2] + a1[3]));
    s2a = fmaf(a0[0], a0[0], s2a); s2a = fmaf(a0[1], a0[1], s2a);
    s2a = fmaf(a0[2], a0[2], s2a); s2a = fmaf(a0[3], a0[3], s2a);
    s2a = fmaf(a1[0], a1[0], s2a); s2a = fmaf(a1[1], a1[1], s2a);
    s2a = fmaf(a1[2], a1[2], s2a); s2a = fmaf(a1[3], a1[3], s2a);
    s1b += ((a2[0] + a2[1]) + (a2[2] + a2[3])) + ((a3[0] + a3[1]) + (a3[2] + a3[3]));
    s2b = fmaf(a2[0], a2[0], s2b); s2b = fmaf(a2[1], a2[1], s2b);
    s2b = fmaf(a2[2], a2[2], s2b); s2b = fmaf(a2[3], a2[3], s2b);
    s2b = fmaf(a3[0], a3[0], s2b); s2b = fmaf(a3[1], a3[1], s2b);
    s2b = fmaf(a3[2], a3[2], s2b); s2b = fmaf(a3[3], a3[3], s2b);
  };

  // ---- prologue: stage k=0, preload a(1) ----
  async_load16(bP[0], BD);
  async_load16(bP[1], BD + 4096);
  bP[0] += 64; bP[1] += 64;
  a0 = *(const f32x4*)aG0; a1 = *(const f32x4*)(aG0 + 4);
  a2 = *(const f32x4*)aG1; a3 = *(const f32x4*)(aG1 + 4);
  packA(0);
  if (nst > 1) {
    aG0 += 32; aG1 += 32;
    a0 = *(const f32x4*)aG0; a1 = *(const f32x4*)(aG0 + 4);
    a2 = *(const f32x4*)aG1; a3 = *(const f32x4*)(aG1 + 4);
  }
  __syncthreads();

  f32x4 acc[4][4] = {};
  for (int k = 0; k < nst; ++k) {
    int cur = k & 1, nxt = cur ^ 1;
    if (k + 1 < nst) {
      async_load16(bP[0], BD + nxt * 8192);
      async_load16(bP[1], BD + nxt * 8192 + 4096);
      bP[0] += 64; bP[1] += 64;
      packA(nxt);
      if (k + 2 < nst) {
        aG0 += 32; aG1 += 32;
        a0 = *(const f32x4*)aG0; a1 = *(const f32x4*)(aG0 + 4);
        a2 = *(const f32x4*)aG1; a3 = *(const f32x4*)(aG1 + 4);
      }
    }
    const char* aF = lds + cur * 8192 + aFoff;
    const char* bF = lds + 16384 + cur * 8192 + bFoff;
    bf16x8 av[4];
#pragma unroll
    for (int rt = 0; rt < 4; ++rt) av[rt] = *(const bf16x8*)(aF + rt * 1024);
#pragma unroll
    for (int ct = 0; ct < 4; ++ct) {
      bf16x8 bv = *(const bf16x8*)(bF + ct * 1024);
#pragma unroll
      for (int rt = 0; rt < 4; ++rt)
        acc[rt][ct] = __builtin_amdgcn_mfma_f32_16x16x32_bf16(av[rt], bv, acc[rt][ct], 0, 0, 0);
    }
    __syncthreads();
  }

  // finish row stats: reduce the 4 granule partials per row
#pragma unroll
  for (int off = 1; off < 4; off <<= 1) {
    s1a += __shfl_xor(s1a, off); s2a += __shfl_xor(s2a, off);
    s1b += __shfl_xor(s1b, off); s2b += __shfl_xor(s2b, off);
  }
  if ((t & 3) == 0) {
    float inv2C = 1.0f / (float)(2 * C);
    float spro = scal[l], sqpro = scal[4 + l];
    float mra = (s1a + spro) * inv2C;
    rowM[rA] = mra;
    rowIS[rA] = rsqrtf((s2a + sqpro) * inv2C - mra * mra + 1e-5f);
    float mrb = (s1b + spro) * inv2C;
    rowM[64 + rA] = mrb;
    rowIS[64 + rA] = rsqrtf((s2b + sqpro) * inv2C - mrb * mrb + 1e-5f);
  }
  __syncthreads();

  // epilogue: h = relu((acc + u - m*G)*invs + B) -> bf16 store
  char* Hl = ws + OFF_H + (size_t)l * 8388608;
#pragma unroll
  for (int rt = 0; rt < 4; ++rt) {
#pragma unroll
    for (int ct = 0; ct < 4; ++ct) {
      int nl = wc + ct * 16 + lc;
      float uu = uArr[nl], gg = gArr[nl], bb = bArr[nl];
      f32x4 a = acc[rt][ct];
#pragma unroll
      for (int reg = 0; reg < 4; ++reg) {
        int ml = wr + rt * 16 + quad * 4 + reg;
        float h = fmaf(a[reg] + uu - rowM[ml] * gg, rowIS[ml], bb);
        h = fmaxf(h, 0.f);
        float hp = __shfl_xor(h, 1);
        if (!(lc & 1)) {
          unsigned pkv = pack2(h, hp);
          *(unsigned*)(Hl + ((size_t)(m0 + ml) * 512 + n0 + nl) * 2) = pkv;
        }
      }
    }
  }
}

// ================= postK: one wave per row, text in registers =================
// 2048 blocks x 4 waves; wave = one row. Lane owns d = lane*8..lane*8+7:
// normalized text slice lives in 16 f32x4 registers -> inner loop is pure FMA,
// one uint4 H load per level. Full-wave shfl reduction of {np, dp[8]}.
__global__ __launch_bounds__(256) void postK(const char* ws, const float* text,
                                             const float* lsc, float* out) {
  int t = threadIdx.x, w = t >> 6, lane = t & 63;
  int row = blockIdx.x * 4 + w;
  int d0 = lane * 8;

  f32x4 tr[16];
#pragma unroll
  for (int k = 0; k < 8; ++k) {
    tr[2 * k]     = *(const f32x4*)(text + k * 512 + d0);
    tr[2 * k + 1] = *(const f32x4*)(text + k * 512 + d0 + 4);
  }
  float nq[8];
#pragma unroll
  for (int k = 0; k < 8; ++k) {
    f32x4 a = tr[2 * k], b = tr[2 * k + 1];
    float s = 0.f;
    s = fmaf(a[0], a[0], s); s = fmaf(a[1], a[1], s);
    s = fmaf(a[2], a[2], s); s = fmaf(a[3], a[3], s);
    s = fmaf(b[0], b[0], s); s = fmaf(b[1], b[1], s);
    s = fmaf(b[2], b[2], s); s = fmaf(b[3], b[3], s);
    nq[k] = s;
  }
#pragma unroll
  for (int off = 1; off < 64; off <<= 1) {
#pragma unroll
    for (int k = 0; k < 8; ++k) nq[k] += __shfl_xor(nq[k], off);
  }
#pragma unroll
  for (int k = 0; k < 8; ++k) {
    float inv = 1.0f / fmaxf(sqrtf(nq[k]), 1e-12f);
    tr[2 * k] *= inv;
    tr[2 * k + 1] *= inv;
  }

  float scale = fmaxf(lsc[0], 1e-4f) * 0.04419417382415922f;  // 1/sqrt(512)
  float lg[4][8];
#pragma unroll
  for (int l = 0; l < 4; ++l) {
    uint4 u = *(const uint4*)(ws + OFF_H + (size_t)l * 8388608 +
                              ((size_t)row * 512 + d0) * 2);
    unsigned uw[4] = {u.x, u.y, u.z, u.w};
    float v[8];
#pragma unroll
    for (int p = 0; p < 4; ++p) {
      v[2 * p]     = __uint_as_float(uw[p] << 16);
      v[2 * p + 1] = __uint_as_float(uw[p] & 0xffff0000u);
    }
    float np = 0.f;
#pragma unroll
    for (int j = 0; j < 8; ++j) np = fmaf(v[j], v[j], np);
    float dp[8];
#pragma unroll
    for (int k = 0; k < 8; ++k) {
      f32x4 ta = tr[2 * k], tb = tr[2 * k + 1];
      float d = 0.f;
      d = fmaf(v[0], ta[0], d); d = fmaf(v[1], ta[1], d);
      d = fmaf(v[2], ta[2], d); d = fmaf(v[3], ta[3], d);
      d = fmaf(v[4], tb[0], d); d = fmaf(v[5], tb[1], d);
      d = fmaf(v[6], tb[2], d); d = fmaf(v[7], tb[3], d);
      dp[k] = d;
    }
#pragma unroll
    for (int off = 1; off < 64; off <<= 1) {
      np += __shfl_xor(np, off);
#pragma unroll
      for (int k = 0; k < 8; ++k) dp[k] += __shfl_xor(dp[k], off);
    }
    float innorm = scale / fmaxf(sqrtf(np), 1e-12f);
#pragma unroll
    for (int k = 0; k < 8; ++k) lg[l][k] = dp[k] * innorm;
  }

  if (lane < 8) {
    float a = lg[0][lane], b2 = lg[1][lane], c = lg[2][lane], d = lg[3][lane];
    float mx = fmaxf(fmaxf(a, b2), fmaxf(c, d));
    float e0 = __expf(a - mx), e1 = __expf(b2 - mx);
    float e2 = __expf(c - mx), e3 = __expf(d - mx);
    float inv = 1.0f / (e0 + e1 + e2 + e3);
    ((float4*)out)[(size_t)row * 8 + lane] = make_float4(e0 * inv, e1 * inv, e2 * inv, e3 * inv);
  }
}

extern "C" void kernel_launch(void* const* d_in, const int* in_sizes, int n_in,
                              void* d_out, int out_size, void* d_ws, size_t ws_size,
                              hipStream_t stream) {
  (void)n_in; (void)out_size;
  if (ws_size < (size_t)WS_TOTAL) return;  // loud failure: output stays poisoned
  char* ws = (char*)d_ws;
  bool dict = (in_sizes[1] == 64 * 256);
  PrepArgs pa;
  for (int l = 0; l < 4; ++l) {
    if (dict) {
      pa.pooled[l] = (const float*)d_in[6 * l + 0];
      pa.proto[l]  = (const float*)d_in[6 * l + 1];
      pa.g[l]      = (const float*)d_in[6 * l + 2];
      pa.beta[l]   = (const float*)d_in[6 * l + 3];
      pa.W[l]      = (const float*)d_in[6 * l + 4];
      pa.bias[l]   = (const float*)d_in[6 * l + 5];
    } else {
      pa.pooled[l] = (const float*)d_in[l];
      pa.proto[l]  = (const float*)d_in[4 + l];
      pa.g[l]      = (const float*)d_in[8 + l];
      pa.beta[l]   = (const float*)d_in[12 + l];
      pa.W[l]      = (const float*)d_in[16 + l];
      pa.bias[l]   = (const float*)d_in[20 + l];
    }
  }
  pa.text = (const float*)d_in[24];
  pa.lsc = (const float*)d_in[25];
  pa.ws = ws;

  // zero the atomic accumulators (U/GG/BB/SCAL are contiguous)
  hipMemsetAsync(ws + OFF_U, 0, 3 * 8192 + 256, stream);
  wtrans<<<480, 256, 0, stream>>>(pa);

  G2Args g2;
  g2.ws = ws;
  for (int l = 0; l < 4; ++l) {
    g2.pooled[l] = pa.pooled[l];
    g2.bias[l] = pa.bias[l];
  }
  gemm2<<<1024, 256, 0, stream>>>(g2);
  postK<<<2048, 256, 0, stream>>>(ws, pa.text, pa.lsc, (float*)d_out);
}

// Round 6
// 385.191 us; speedup vs baseline: 1.0576x; 1.0576x over previous
//
#include <hip/hip_runtime.h>
#include <stdint.h>

typedef __bf16 bf16x8 __attribute__((ext_vector_type(8)));
typedef float f32x4 __attribute__((ext_vector_type(4)));

// ---- workspace byte offsets ----
#define OFF_ABF   0u           // pooled as bf16, per level [8192][C]
#define OFF_GWT   62914560u    // (g*W)^T bf16 per level [512][C]
#define OFF_LOG   66846720u    // f32 [4][8192][16]: k=0..7 dots, k=8 ||h||^2 (zeroed)
#define OFF_STAT  100401152u   // per (l,row): sum, sumsq  (4*8192*2 f32)
#define OFF_TEXT  100663296u   // 4096 f32 normalized text
#define OFF_U     100679680u   // 4*512 f32 (zeroed, atomic-accumulated)
#define OFF_GG    100687872u
#define OFF_BB    100696064u
#define OFF_SCAL  100704256u   // [0..3] sproto, [4..7] sqproto (zeroed)
#define WS_TOTAL  100719872u

__host__ __device__ __forceinline__ size_t abf_off(int l) {
  return (size_t)4194304u * (size_t)((1u << l) - 1u);
}
__host__ __device__ __forceinline__ size_t gwt_off(int l) {
  return (size_t)262144u * (size_t)((1u << l) - 1u);
}

__device__ __forceinline__ unsigned short f2bf(float x) {
  return (unsigned short)((__float_as_uint(x) + 0x8000u) >> 16);
}
__device__ __forceinline__ unsigned pack2(float a, float b) {
  return ((__float_as_uint(a) + 0x8000u) >> 16) |
         ((__float_as_uint(b) + 0x8000u) & 0xffff0000u);
}
__device__ __forceinline__ void async_load16(const void* g, void* l) {
  __builtin_amdgcn_global_load_lds((const __attribute__((address_space(1))) void*)g,
                                   (__attribute__((address_space(3))) void*)l,
                                   16, 0, 0);
}

struct PrepArgs {
  const float* pooled[4];
  const float* proto[4];
  const float* W[4];
  const float* g[4];
  const float* beta[4];
  const float* bias[4];
  const float* text;
  const float* lsc;
  char* ws;
};

// ================= aconv: register-staged streaming convert + row stats =================
// (R2 version, measured 66.8 us — unchanged control; tail blocks moved out)
__device__ __forceinline__ void loadUnit(f32x4 (&buf)[8], const f32x4* base, int lane) {
#pragma unroll
  for (int i = 0; i < 4; ++i) {
    buf[2 * i]     = base[2 * (lane + 64 * i)];
    buf[2 * i + 1] = base[2 * (lane + 64 * i) + 1];
  }
}

template <int R>
__device__ __forceinline__ void procUnit(const f32x4 (&v)[8], char* Dst, float* st,
                                         int rowBase, int lane) {
  float p1[4], p2[4];
#pragma unroll
  for (int i = 0; i < 4; ++i) {
    f32x4 a = v[2 * i], b = v[2 * i + 1];
    float s1 = ((a[0] + a[1]) + (a[2] + a[3])) + ((b[0] + b[1]) + (b[2] + b[3]));
    float s2 = 0.f;
    s2 = fmaf(a[0], a[0], s2); s2 = fmaf(a[1], a[1], s2);
    s2 = fmaf(a[2], a[2], s2); s2 = fmaf(a[3], a[3], s2);
    s2 = fmaf(b[0], b[0], s2); s2 = fmaf(b[1], b[1], s2);
    s2 = fmaf(b[2], b[2], s2); s2 = fmaf(b[3], b[3], s2);
    p1[i] = s1; p2[i] = s2;
    uint4 o = make_uint4(pack2(a[0], a[1]), pack2(a[2], a[3]),
                         pack2(b[0], b[1]), pack2(b[2], b[3]));
    *(uint4*)(Dst + 16 * (size_t)(lane + 64 * i)) = o;
  }
  if constexpr (R == 1) {
    float s1 = (p1[0] + p1[1]) + (p1[2] + p1[3]);
    float s2 = (p2[0] + p2[1]) + (p2[2] + p2[3]);
#pragma unroll
    for (int off = 1; off < 64; off <<= 1) {
      s1 += __shfl_xor(s1, off); s2 += __shfl_xor(s2, off);
    }
    if (lane == 0) {
      st[2 * (size_t)rowBase] = s1; st[2 * (size_t)rowBase + 1] = s2;
    }
  } else if constexpr (R == 2) {
#pragma unroll
    for (int h = 0; h < 2; ++h) {
      float s1 = p1[2 * h] + p1[2 * h + 1], s2 = p2[2 * h] + p2[2 * h + 1];
#pragma unroll
      for (int off = 1; off < 64; off <<= 1) {
        s1 += __shfl_xor(s1, off); s2 += __shfl_xor(s2, off);
      }
      if (lane == 0) {
        st[2 * (size_t)(rowBase + h)] = s1; st[2 * (size_t)(rowBase + h) + 1] = s2;
      }
    }
  } else if constexpr (R == 4) {
#pragma unroll
    for (int i = 0; i < 4; ++i) {
      float s1 = p1[i], s2 = p2[i];
#pragma unroll
      for (int off = 1; off < 64; off <<= 1) {
        s1 += __shfl_xor(s1, off); s2 += __shfl_xor(s2, off);
      }
      if (lane == 0) {
        st[2 * (size_t)(rowBase + i)] = s1; st[2 * (size_t)(rowBase + i) + 1] = s2;
      }
    }
  } else {  // R == 8: lanes 0-31 hold row 2i, lanes 32-63 row 2i+1
#pragma unroll
    for (int i = 0; i < 4; ++i) {
      float s1 = p1[i], s2 = p2[i];
#pragma unroll
      for (int off = 1; off < 32; off <<= 1) {
        s1 += __shfl_xor(s1, off); s2 += __shfl_xor(s2, off);
      }
      if ((lane & 31) == 0) {
        int row = rowBase + 2 * i + (lane >> 5);
        st[2 * (size_t)row] = s1; st[2 * (size_t)row + 1] = s2;
      }
    }
  }
}

template <int R>
__device__ __forceinline__ void waveRun(const f32x4* P, char* Dst, float* st,
                                        int rowBase, int lane) {
  f32x4 bufA[8], bufB[8];
  loadUnit(bufA, P, lane);
#pragma unroll
  for (int k = 0; k < 8; ++k) {
    if ((k & 1) == 0) {
      if (k < 7) loadUnit(bufB, P + (size_t)(k + 1) * 512, lane);
      procUnit<R>(bufA, Dst + (size_t)k * 4096, st, rowBase + k * R, lane);
    } else {
      if (k < 7) loadUnit(bufA, P + (size_t)(k + 1) * 512, lane);
      procUnit<R>(bufB, Dst + (size_t)k * 4096, st, rowBase + k * R, lane);
    }
  }
}

__global__ __launch_bounds__(256, 4) void aconv(PrepArgs A) {
  int t = threadIdx.x, bid = blockIdx.x;
  int w = t >> 6, lane = t & 63;
  // unit ids: l=3: [0,8192)  l=2: [8192,12288)  l=1: [12288,14336)  l=0: [14336,15360)
  int u0 = (bid * 4 + w) * 8;
  int l, uL;
  if (u0 < 8192)       { l = 3; uL = u0; }
  else if (u0 < 12288) { l = 2; uL = u0 - 8192; }
  else if (u0 < 14336) { l = 1; uL = u0 - 12288; }
  else                 { l = 0; uL = u0 - 14336; }
  const f32x4* P = (const f32x4*)A.pooled[l] + (size_t)uL * 512;
  char* Dst = A.ws + OFF_ABF + abf_off(l) + (size_t)uL * 4096;
  float* st = (float*)(A.ws + OFF_STAT) + (size_t)l * 8192 * 2;
  if (l == 3)      waveRun<1>(P, Dst, st, uL,     lane);
  else if (l == 2) waveRun<2>(P, Dst, st, uL * 2, lane);
  else if (l == 1) waveRun<4>(P, Dst, st, uL * 4, lane);
  else             waveRun<8>(P, Dst, st, uL * 8, lane);
}

// ================= wtrans: W-slab transpose + Gsum/Bsum/u + pmean/scal + text =================
// 481 blocks: 480 W-slabs (64j x 128d) + 1 text-normalization block.
__global__ __launch_bounds__(256) void wtrans(PrepArgs A) {
  __shared__ unsigned short tile[128][66];     // padded: 2-way-only banking
  __shared__ float redG[4][128], redB[4][128], redU[4][128];
  __shared__ float gsh[64], bsh[64], psh[64];
  __shared__ float redP[4][64];
  int t = threadIdx.x, bid = blockIdx.x;

  if (bid == 480) {
    // ---- text l2norm: 8 rows x 512, 32 lanes/row ----
    int row = t >> 5, l32 = t & 31;
    const float* tr = A.text + row * 512 + l32;
    float v[16];
    float s = 0.f;
#pragma unroll
    for (int i = 0; i < 16; ++i) {
      v[i] = tr[32 * i];
      s = fmaf(v[i], v[i], s);
    }
#pragma unroll
    for (int off = 1; off < 32; off <<= 1) s += __shfl_xor(s, off);
    float inv = 1.0f / fmaxf(sqrtf(s), 1e-12f);
    float* tf = (float*)(A.ws + OFF_TEXT) + row * 512 + l32;
#pragma unroll
    for (int i = 0; i < 16; ++i) tf[32 * i] = v[i] * inv;
    return;
  }

  int l, idl;
  if (bid < 256)      { l = 3; idl = bid; }
  else if (bid < 384) { l = 2; idl = bid - 256; }
  else if (bid < 448) { l = 1; idl = bid - 384; }
  else                { l = 0; idl = bid - 448; }
  int C = 256 << l;
  int sid = idl >> 2, dchunk = idl & 3;
  int j0 = sid * 64, d0 = dchunk * 128;
  bool top = (j0 < C);
  int w = t >> 6, L = t & 63;
  float* scal = (float*)(A.ws + OFF_SCAL);

  if (t < 64) {
    gsh[t] = A.g[l][j0 + t];
    bsh[t] = A.beta[l][j0 + t];
  }
  if (!top) {
    const float* pr = A.proto[l];
    int cb0 = j0 - C;
    float s = 0.f;
#pragma unroll
    for (int r = 0; r < 16; ++r) s += pr[(size_t)(w * 16 + r) * C + cb0 + L];
    redP[w][L] = s;
  }
  __syncthreads();
  if (!top) {
    if (t < 64) {
      float pmv = (redP[0][t] + redP[1][t] + redP[2][t] + redP[3][t]) * (1.0f / 64.0f);
      psh[t] = pmv * gsh[t];
      if (dchunk == 0) {
        float s1 = pmv, s2 = pmv * pmv;
#pragma unroll
        for (int off = 1; off < 64; off <<= 1) {
          s1 += __shfl_xor(s1, off);
          s2 += __shfl_xor(s2, off);
        }
        if (t == 0) {
          atomicAdd(&scal[l], s1);
          atomicAdd(&scal[4 + l], s2);
        }
      }
    }
    __syncthreads();
  }

  const float* W = A.W[l];
  float2 v[16];
#pragma unroll
  for (int r = 0; r < 16; ++r) {
    int j = j0 + w * 16 + r;
    v[r] = *(const float2*)(W + (size_t)j * 512 + d0 + 2 * L);
  }
  float gp0 = 0.f, gp1 = 0.f, bp0 = 0.f, bp1 = 0.f, up0 = 0.f, up1 = 0.f;
#pragma unroll
  for (int r = 0; r < 16; ++r) {
    int jl = w * 16 + r;
    float g = gsh[jl], b = bsh[jl];
    gp0 = fmaf(g, v[r].x, gp0); gp1 = fmaf(g, v[r].y, gp1);
    bp0 = fmaf(b, v[r].x, bp0); bp1 = fmaf(b, v[r].y, bp1);
    if (top) {
      tile[2 * L][jl] = f2bf(g * v[r].x);
      tile[2 * L + 1][jl] = f2bf(g * v[r].y);
    } else {
      float p = psh[jl];
      up0 = fmaf(p, v[r].x, up0); up1 = fmaf(p, v[r].y, up1);
    }
  }
  redG[w][2 * L] = gp0; redG[w][2 * L + 1] = gp1;
  redB[w][2 * L] = bp0; redB[w][2 * L + 1] = bp1;
  if (!top) { redU[w][2 * L] = up0; redU[w][2 * L + 1] = up1; }
  __syncthreads();

  if (t < 128) {
    int d = l * 512 + d0 + t;
    float G = redG[0][t] + redG[1][t] + redG[2][t] + redG[3][t];
    float B = redB[0][t] + redB[1][t] + redB[2][t] + redB[3][t];
    atomicAdd(&((float*)(A.ws + OFF_GG))[d], G);
    atomicAdd(&((float*)(A.ws + OFF_BB))[d], B);
    if (!top) {
      float U = redU[0][t] + redU[1][t] + redU[2][t] + redU[3][t];
      atomicAdd(&((float*)(A.ws + OFF_U))[d], U);
    }
  }
  if (top) {
    unsigned short* gwT = (unsigned short*)(A.ws + OFF_GWT + gwt_off(l));
    int d = t >> 1, jh = (t & 1) * 32;
    const unsigned* trow = (const unsigned*)&tile[d][jh];  // 4B-aligned
    uint4 q0 = make_uint4(trow[0], trow[1], trow[2], trow[3]);
    uint4 q1 = make_uint4(trow[4], trow[5], trow[6], trow[7]);
    uint4 q2 = make_uint4(trow[8], trow[9], trow[10], trow[11]);
    uint4 q3 = make_uint4(trow[12], trow[13], trow[14], trow[15]);
    uint4* dst = (uint4*)(gwT + (size_t)(d0 + d) * C + j0 + jh);
    dst[0] = q0; dst[1] = q1; dst[2] = q2; dst[3] = q3;
  }
}

// ================= gemm2: R2 core + XCD swizzle + fused logit-dot epilogue =================
// Core: m97 2-barrier loop, global_load_lds for A (ABF bf16) and B (GWT bf16).
// XCD swizzle: bid = ((blockIdx.x&7)<<7)+(blockIdx.x>>3) — cb-siblings share an
// XCD so A panels and the level's B panels are L2-resident (R4: FETCH 250->69MB).
// Epilogue: NO H write. h stays f32; each block accumulates its tile's partial
// text-dots (k=0..7) and ||h||^2 (k=8) into OFF_LOG via lc-shuffle + atomicAdd.
struct G2Args {
  char* ws;
  const float* bias[4];
};

__global__ __launch_bounds__(256, 3) void gemm2(G2Args A) {
  __shared__ __align__(16) char lds[23040];
  char* ws = A.ws;
  int t = threadIdx.x;
  int bid = ((blockIdx.x & 7) << 7) + (blockIdx.x >> 3);   // XCD chunking
  int l = 3 - (bid >> 8);          // heavy levels first
  int rb = (bid >> 2) & 63, cb = bid & 3;
  int C = 256 << l;
  int m0 = rb * 128, n0 = cb * 128;

  float* uArr  = (float*)(lds + 16384);
  float* gArr  = (float*)(lds + 16896);
  float* bArr  = (float*)(lds + 17408);
  float* rowM  = (float*)(lds + 17920);
  float* rowIS = (float*)(lds + 18432);
  float* textL = (float*)(lds + 18944);   // [8][128]
  const float* scal = (const float*)(ws + OFF_SCAL);

  if (t < 128) {
    int idx = l * 512 + n0 + t;
    uArr[t] = ((const float*)(ws + OFF_U))[idx];
    gArr[t] = ((const float*)(ws + OFF_GG))[idx];
    bArr[t] = ((const float*)(ws + OFF_BB))[idx] + A.bias[l][n0 + t];
  } else {
    int r = t - 128;
    const float* st = (const float*)(ws + OFF_STAT) + (size_t)(l * 8192 + m0 + r) * 2;
    float s1 = st[0], s2 = st[1];
    float inv2C = 1.0f / (float)(2 * C);
    float mr = (s1 + scal[l]) * inv2C;
    float var = (s2 + scal[4 + l]) * inv2C - mr * mr;
    rowM[r] = mr;
    rowIS[r] = rsqrtf(var + 1e-5f);
  }
  {
    const float* tf = (const float*)(ws + OFF_TEXT);
#pragma unroll
    for (int i = 0; i < 4; ++i) {
      int idx = t + 256 * i;          // 0..1023 -> [8][128]
      textL[idx] = tf[(idx >> 7) * 512 + n0 + (idx & 127)];
    }
  }

  int w = t >> 6, lane = t & 63, quad = lane >> 4, lc = lane & 15;
  const char* Abf = ws + OFF_ABF + abf_off(l);
  const char* Bw  = ws + OFF_GWT + gwt_off(l);
  const char* aP[2]; const char* bP[2];
  char* aD[2]; char* bD[2];
#pragma unroll
  for (int i = 0; i < 2; ++i) {
    int li = i * 256 + t;
    int rr = li >> 2, kq = li & 3;
    aP[i] = Abf + ((size_t)(m0 + rr) * C + kq * 8) * 2;
    bP[i] = Bw  + ((size_t)(n0 + rr) * C + kq * 8) * 2;
    aD[i] = lds + i * 4096 + w * 1024;
    bD[i] = lds + 8192 + i * 4096 + w * 1024;
  }
  int wr = (w >> 1) * 64, wc = (w & 1) * 64;
  const char* aF = lds + (wr + lc) * 64 + quad * 16;
  const char* bF = lds + 8192 + (wc + lc) * 64 + quad * 16;

  f32x4 acc[4][4] = {};
  for (int k0 = 0; k0 < C; k0 += 32) {
    async_load16(aP[0], aD[0]); async_load16(aP[1], aD[1]);
    async_load16(bP[0], bD[0]); async_load16(bP[1], bD[1]);
    aP[0] += 64; aP[1] += 64; bP[0] += 64; bP[1] += 64;
    __syncthreads();
    bf16x8 av[4];
#pragma unroll
    for (int rt = 0; rt < 4; ++rt) av[rt] = *(const bf16x8*)(aF + rt * 1024);
#pragma unroll
    for (int ct = 0; ct < 4; ++ct) {
      bf16x8 bv = *(const bf16x8*)(bF + ct * 1024);
#pragma unroll
      for (int rt = 0; rt < 4; ++rt)
        acc[rt][ct] = __builtin_amdgcn_mfma_f32_16x16x32_bf16(av[rt], bv, acc[rt][ct], 0, 0, 0);
    }
    __syncthreads();
  }

  // epilogue: h = relu((acc + u - m*G)*invs + B); accumulate text dots + ||h||^2
#pragma unroll
  for (int rt = 0; rt < 4; ++rt) {
#pragma unroll
    for (int reg = 0; reg < 4; ++reg) {
      int ml = wr + rt * 16 + quad * 4 + reg;
      float rm = rowM[ml], ris = rowIS[ml];
      float p[9] = {};
#pragma unroll
      for (int ct = 0; ct < 4; ++ct) {
        int nl = wc + ct * 16 + lc;
        float h = fmaf(acc[rt][ct][reg] + uArr[nl] - rm * gArr[nl], ris, bArr[nl]);
        h = fmaxf(h, 0.f);
        p[8] = fmaf(h, h, p[8]);
#pragma unroll
        for (int k = 0; k < 8; ++k)
          p[k] = fmaf(h, textL[k * 128 + nl], p[k]);
      }
#pragma unroll
      for (int off = 1; off < 16; off <<= 1) {
#pragma unroll
        for (int k = 0; k < 9; ++k) p[k] += __shfl_xor(p[k], off);
      }
      if (lc == 0) {
        float* Lg = (float*)(ws + OFF_LOG) + (((size_t)l * 8192 + m0 + ml) << 4);
#pragma unroll
        for (int k = 0; k < 9; ++k) atomicAdd(&Lg[k], p[k]);
      }
    }
  }
}

// ================= finishK: normalize + scale + softmax over levels =================
__global__ __launch_bounds__(256) void finishK(const char* ws, const float* lsc,
                                               float* out) {
  int t = threadIdx.x;
  int row = blockIdx.x * 32 + (t >> 3), k = t & 7;
  float scale = fmaxf(lsc[0], 1e-4f) * 0.04419417382415922f;  // 1/sqrt(512)
  float x[4];
#pragma unroll
  for (int l = 0; l < 4; ++l) {
    const float* Lg = (const float*)(ws + OFF_LOG) + (((size_t)l * 8192 + row) << 4);
    float dot = Lg[k], nsq = Lg[8];
    x[l] = dot * (scale / fmaxf(sqrtf(nsq), 1e-12f));
  }
  float mx = fmaxf(fmaxf(x[0], x[1]), fmaxf(x[2], x[3]));
  float e0 = __expf(x[0] - mx), e1 = __expf(x[1] - mx);
  float e2 = __expf(x[2] - mx), e3 = __expf(x[3] - mx);
  float inv = 1.0f / (e0 + e1 + e2 + e3);
  ((float4*)out)[(size_t)row * 8 + k] = make_float4(e0 * inv, e1 * inv, e2 * inv, e3 * inv);
}

extern "C" void kernel_launch(void* const* d_in, const int* in_sizes, int n_in,
                              void* d_out, int out_size, void* d_ws, size_t ws_size,
                              hipStream_t stream) {
  (void)n_in; (void)out_size;
  if (ws_size < (size_t)WS_TOTAL) return;  // loud failure: output stays poisoned
  char* ws = (char*)d_ws;
  bool dict = (in_sizes[1] == 64 * 256);
  PrepArgs pa;
  for (int l = 0; l < 4; ++l) {
    if (dict) {
      pa.pooled[l] = (const float*)d_in[6 * l + 0];
      pa.proto[l]  = (const float*)d_in[6 * l + 1];
      pa.g[l]      = (const float*)d_in[6 * l + 2];
      pa.beta[l]   = (const float*)d_in[6 * l + 3];
      pa.W[l]      = (const float*)d_in[6 * l + 4];
      pa.bias[l]   = (const float*)d_in[6 * l + 5];
    } else {
      pa.pooled[l] = (const float*)d_in[l];
      pa.proto[l]  = (const float*)d_in[4 + l];
      pa.g[l]      = (const float*)d_in[8 + l];
      pa.beta[l]   = (const float*)d_in[12 + l];
      pa.W[l]      = (const float*)d_in[16 + l];
      pa.bias[l]   = (const float*)d_in[20 + l];
    }
  }
  pa.text = (const float*)d_in[24];
  pa.lsc = (const float*)d_in[25];
  pa.ws = ws;

  // zero the atomic accumulators: U/GG/BB/SCAL block + logits block
  hipMemsetAsync(ws + OFF_U, 0, 3 * 8192 + 256, stream);
  hipMemsetAsync(ws + OFF_LOG, 0, 4 * 8192 * 16 * 4, stream);

  aconv<<<480, 256, 0, stream>>>(pa);
  wtrans<<<481, 256, 0, stream>>>(pa);

  G2Args g2;
  g2.ws = ws;
  for (int l = 0; l < 4; ++l) g2.bias[l] = pa.bias[l];
  gemm2<<<1024, 256, 0, stream>>>(g2);
  finishK<<<256, 256, 0, stream>>>(ws, pa.lsc, (float*)d_out);
}

// Round 7
// 314.159 us; speedup vs baseline: 1.2967x; 1.2261x over previous
//
#include <hip/hip_runtime.h>
#include <stdint.h>

typedef __bf16 bf16x8 __attribute__((ext_vector_type(8)));
typedef float f32x4 __attribute__((ext_vector_type(4)));

// ---- workspace byte offsets ----
#define OFF_ABF   0u           // pooled as bf16, per level [8192][C]
#define OFF_GWT   62914560u    // (g*W)^T bf16 per level [512][C]
#define OFF_LOG   66846720u    // f32 [4][8192][8][16]: private partial slots (no atomics)
#define OFF_STAT  100401152u   // per (l,row): sum, sumsq  (4*8192*2 f32)
#define OFF_TEXT  100663296u   // 4096 f32 normalized text
#define OFF_U     100679680u   // 4*512 f32 (zeroed, atomic-accumulated)
#define OFF_GG    100687872u
#define OFF_BB    100696064u
#define OFF_SCAL  100704256u   // [0..3] sproto, [4..7] sqproto (zeroed)
#define WS_TOTAL  100719872u

__host__ __device__ __forceinline__ size_t abf_off(int l) {
  return (size_t)4194304u * (size_t)((1u << l) - 1u);
}
__host__ __device__ __forceinline__ size_t gwt_off(int l) {
  return (size_t)262144u * (size_t)((1u << l) - 1u);
}

__device__ __forceinline__ unsigned short f2bf(float x) {
  return (unsigned short)((__float_as_uint(x) + 0x8000u) >> 16);
}
__device__ __forceinline__ unsigned pack2(float a, float b) {
  return ((__float_as_uint(a) + 0x8000u) >> 16) |
         ((__float_as_uint(b) + 0x8000u) & 0xffff0000u);
}
__device__ __forceinline__ void async_load16(const void* g, void* l) {
  __builtin_amdgcn_global_load_lds((const __attribute__((address_space(1))) void*)g,
                                   (__attribute__((address_space(3))) void*)l,
                                   16, 0, 0);
}

struct PrepArgs {
  const float* pooled[4];
  const float* proto[4];
  const float* W[4];
  const float* g[4];
  const float* beta[4];
  const float* bias[4];
  const float* text;
  const float* lsc;
  char* ws;
};

// ================= aconv: one 8KB unit per wave, pure TLP =================
// 8 independent dwordx4 loads/lane fit in-flight within a ~56-VGPR allocation
// (single waitcnt; no compiler batching — the R0/R2 failure was 16-load waves
// at 48 VGPRs). Grid 3840 -> ~30 waves/CU hide the HBM latency.
__device__ __forceinline__ void loadUnit(f32x4 (&buf)[8], const f32x4* base, int lane) {
#pragma unroll
  for (int i = 0; i < 4; ++i) {
    buf[2 * i]     = base[2 * (lane + 64 * i)];
    buf[2 * i + 1] = base[2 * (lane + 64 * i) + 1];
  }
}

template <int R>
__device__ __forceinline__ void procUnit(const f32x4 (&v)[8], char* Dst, float* st,
                                         int rowBase, int lane) {
  float p1[4], p2[4];
#pragma unroll
  for (int i = 0; i < 4; ++i) {
    f32x4 a = v[2 * i], b = v[2 * i + 1];
    float s1 = ((a[0] + a[1]) + (a[2] + a[3])) + ((b[0] + b[1]) + (b[2] + b[3]));
    float s2 = 0.f;
    s2 = fmaf(a[0], a[0], s2); s2 = fmaf(a[1], a[1], s2);
    s2 = fmaf(a[2], a[2], s2); s2 = fmaf(a[3], a[3], s2);
    s2 = fmaf(b[0], b[0], s2); s2 = fmaf(b[1], b[1], s2);
    s2 = fmaf(b[2], b[2], s2); s2 = fmaf(b[3], b[3], s2);
    p1[i] = s1; p2[i] = s2;
    uint4 o = make_uint4(pack2(a[0], a[1]), pack2(a[2], a[3]),
                         pack2(b[0], b[1]), pack2(b[2], b[3]));
    *(uint4*)(Dst + 16 * (size_t)(lane + 64 * i)) = o;
  }
  if constexpr (R == 1) {
    float s1 = (p1[0] + p1[1]) + (p1[2] + p1[3]);
    float s2 = (p2[0] + p2[1]) + (p2[2] + p2[3]);
#pragma unroll
    for (int off = 1; off < 64; off <<= 1) {
      s1 += __shfl_xor(s1, off); s2 += __shfl_xor(s2, off);
    }
    if (lane == 0) {
      st[2 * (size_t)rowBase] = s1; st[2 * (size_t)rowBase + 1] = s2;
    }
  } else if constexpr (R == 2) {
#pragma unroll
    for (int h = 0; h < 2; ++h) {
      float s1 = p1[2 * h] + p1[2 * h + 1], s2 = p2[2 * h] + p2[2 * h + 1];
#pragma unroll
      for (int off = 1; off < 64; off <<= 1) {
        s1 += __shfl_xor(s1, off); s2 += __shfl_xor(s2, off);
      }
      if (lane == 0) {
        st[2 * (size_t)(rowBase + h)] = s1; st[2 * (size_t)(rowBase + h) + 1] = s2;
      }
    }
  } else if constexpr (R == 4) {
#pragma unroll
    for (int i = 0; i < 4; ++i) {
      float s1 = p1[i], s2 = p2[i];
#pragma unroll
      for (int off = 1; off < 64; off <<= 1) {
        s1 += __shfl_xor(s1, off); s2 += __shfl_xor(s2, off);
      }
      if (lane == 0) {
        st[2 * (size_t)(rowBase + i)] = s1; st[2 * (size_t)(rowBase + i) + 1] = s2;
      }
    }
  } else {  // R == 8: lanes 0-31 hold row 2i, lanes 32-63 row 2i+1
#pragma unroll
    for (int i = 0; i < 4; ++i) {
      float s1 = p1[i], s2 = p2[i];
#pragma unroll
      for (int off = 1; off < 32; off <<= 1) {
        s1 += __shfl_xor(s1, off); s2 += __shfl_xor(s2, off);
      }
      if ((lane & 31) == 0) {
        int row = rowBase + 2 * i + (lane >> 5);
        st[2 * (size_t)row] = s1; st[2 * (size_t)row + 1] = s2;
      }
    }
  }
}

__global__ __launch_bounds__(256, 4) void aconv(PrepArgs A) {
  int t = threadIdx.x, bid = blockIdx.x;
  int w = t >> 6, lane = t & 63;
  // unit ids: l=3: [0,8192)  l=2: [8192,12288)  l=1: [12288,14336)  l=0: [14336,15360)
  int u0 = bid * 4 + w;   // ONE unit per wave
  int l, uL;
  if (u0 < 8192)       { l = 3; uL = u0; }
  else if (u0 < 12288) { l = 2; uL = u0 - 8192; }
  else if (u0 < 14336) { l = 1; uL = u0 - 12288; }
  else                 { l = 0; uL = u0 - 14336; }
  const f32x4* P = (const f32x4*)A.pooled[l] + (size_t)uL * 512;
  char* Dst = A.ws + OFF_ABF + abf_off(l) + (size_t)uL * 4096;
  float* st = (float*)(A.ws + OFF_STAT) + (size_t)l * 8192 * 2;
  f32x4 v[8];
  loadUnit(v, P, lane);
  if (l == 3)      procUnit<1>(v, Dst, st, uL,     lane);
  else if (l == 2) procUnit<2>(v, Dst, st, uL * 2, lane);
  else if (l == 1) procUnit<4>(v, Dst, st, uL * 4, lane);
  else             procUnit<8>(v, Dst, st, uL * 8, lane);
}

// ================= wtrans: W-slab transpose + Gsum/Bsum/u + pmean/scal + text =================
// 481 blocks: 480 W-slabs (64j x 128d) + 1 text-normalization block. (unchanged)
__global__ __launch_bounds__(256) void wtrans(PrepArgs A) {
  __shared__ unsigned short tile[128][66];     // padded: 2-way-only banking
  __shared__ float redG[4][128], redB[4][128], redU[4][128];
  __shared__ float gsh[64], bsh[64], psh[64];
  __shared__ float redP[4][64];
  int t = threadIdx.x, bid = blockIdx.x;

  if (bid == 480) {
    // ---- text l2norm: 8 rows x 512, 32 lanes/row ----
    int row = t >> 5, l32 = t & 31;
    const float* tr = A.text + row * 512 + l32;
    float v[16];
    float s = 0.f;
#pragma unroll
    for (int i = 0; i < 16; ++i) {
      v[i] = tr[32 * i];
      s = fmaf(v[i], v[i], s);
    }
#pragma unroll
    for (int off = 1; off < 32; off <<= 1) s += __shfl_xor(s, off);
    float inv = 1.0f / fmaxf(sqrtf(s), 1e-12f);
    float* tf = (float*)(A.ws + OFF_TEXT) + row * 512 + l32;
#pragma unroll
    for (int i = 0; i < 16; ++i) tf[32 * i] = v[i] * inv;
    return;
  }

  int l, idl;
  if (bid < 256)      { l = 3; idl = bid; }
  else if (bid < 384) { l = 2; idl = bid - 256; }
  else if (bid < 448) { l = 1; idl = bid - 384; }
  else                { l = 0; idl = bid - 448; }
  int C = 256 << l;
  int sid = idl >> 2, dchunk = idl & 3;
  int j0 = sid * 64, d0 = dchunk * 128;
  bool top = (j0 < C);
  int w = t >> 6, L = t & 63;
  float* scal = (float*)(A.ws + OFF_SCAL);

  if (t < 64) {
    gsh[t] = A.g[l][j0 + t];
    bsh[t] = A.beta[l][j0 + t];
  }
  if (!top) {
    const float* pr = A.proto[l];
    int cb0 = j0 - C;
    float s = 0.f;
#pragma unroll
    for (int r = 0; r < 16; ++r) s += pr[(size_t)(w * 16 + r) * C + cb0 + L];
    redP[w][L] = s;
  }
  __syncthreads();
  if (!top) {
    if (t < 64) {
      float pmv = (redP[0][t] + redP[1][t] + redP[2][t] + redP[3][t]) * (1.0f / 64.0f);
      psh[t] = pmv * gsh[t];
      if (dchunk == 0) {
        float s1 = pmv, s2 = pmv * pmv;
#pragma unroll
        for (int off = 1; off < 64; off <<= 1) {
          s1 += __shfl_xor(s1, off);
          s2 += __shfl_xor(s2, off);
        }
        if (t == 0) {
          atomicAdd(&scal[l], s1);
          atomicAdd(&scal[4 + l], s2);
        }
      }
    }
    __syncthreads();
  }

  const float* W = A.W[l];
  float2 v[16];
#pragma unroll
  for (int r = 0; r < 16; ++r) {
    int j = j0 + w * 16 + r;
    v[r] = *(const float2*)(W + (size_t)j * 512 + d0 + 2 * L);
  }
  float gp0 = 0.f, gp1 = 0.f, bp0 = 0.f, bp1 = 0.f, up0 = 0.f, up1 = 0.f;
#pragma unroll
  for (int r = 0; r < 16; ++r) {
    int jl = w * 16 + r;
    float g = gsh[jl], b = bsh[jl];
    gp0 = fmaf(g, v[r].x, gp0); gp1 = fmaf(g, v[r].y, gp1);
    bp0 = fmaf(b, v[r].x, bp0); bp1 = fmaf(b, v[r].y, bp1);
    if (top) {
      tile[2 * L][jl] = f2bf(g * v[r].x);
      tile[2 * L + 1][jl] = f2bf(g * v[r].y);
    } else {
      float p = psh[jl];
      up0 = fmaf(p, v[r].x, up0); up1 = fmaf(p, v[r].y, up1);
    }
  }
  redG[w][2 * L] = gp0; redG[w][2 * L + 1] = gp1;
  redB[w][2 * L] = bp0; redB[w][2 * L + 1] = bp1;
  if (!top) { redU[w][2 * L] = up0; redU[w][2 * L + 1] = up1; }
  __syncthreads();

  if (t < 128) {
    int d = l * 512 + d0 + t;
    float G = redG[0][t] + redG[1][t] + redG[2][t] + redG[3][t];
    float B = redB[0][t] + redB[1][t] + redB[2][t] + redB[3][t];
    atomicAdd(&((float*)(A.ws + OFF_GG))[d], G);
    atomicAdd(&((float*)(A.ws + OFF_BB))[d], B);
    if (!top) {
      float U = redU[0][t] + redU[1][t] + redU[2][t] + redU[3][t];
      atomicAdd(&((float*)(A.ws + OFF_U))[d], U);
    }
  }
  if (top) {
    unsigned short* gwT = (unsigned short*)(A.ws + OFF_GWT + gwt_off(l));
    int d = t >> 1, jh = (t & 1) * 32;
    const unsigned* trow = (const unsigned*)&tile[d][jh];  // 4B-aligned
    uint4 q0 = make_uint4(trow[0], trow[1], trow[2], trow[3]);
    uint4 q1 = make_uint4(trow[4], trow[5], trow[6], trow[7]);
    uint4 q2 = make_uint4(trow[8], trow[9], trow[10], trow[11]);
    uint4 q3 = make_uint4(trow[12], trow[13], trow[14], trow[15]);
    uint4* dst = (uint4*)(gwT + (size_t)(d0 + d) * C + j0 + jh);
    dst[0] = q0; dst[1] = q1; dst[2] = q2; dst[3] = q3;
  }
}

// ================= gemm2: R2 core + XCD swizzle + fused epilogue (private slots) =================
// Core: m97 2-barrier loop, global_load_lds for A (ABF bf16) and B (GWT bf16).
// XCD swizzle: cb-siblings share an XCD -> panels L2-resident (R4: FETCH 250->69MB).
// Epilogue: NO H write, NO atomics (R6 lesson: 2.36M contended device atomics =
// +110us, 72MB write-through). Each (l,row,cb,wave-half) partial has exactly one
// producer -> plain stores into private slot [4][8192][8][16]; finishK reduces.
struct G2Args {
  char* ws;
  const float* bias[4];
};

__global__ __launch_bounds__(256, 3) void gemm2(G2Args A) {
  __shared__ __align__(16) char lds[23040];
  char* ws = A.ws;
  int t = threadIdx.x;
  int bid = ((blockIdx.x & 7) << 7) + (blockIdx.x >> 3);   // XCD chunking
  int l = 3 - (bid >> 8);          // heavy levels first
  int rb = (bid >> 2) & 63, cb = bid & 3;
  int C = 256 << l;
  int m0 = rb * 128, n0 = cb * 128;

  float* uArr  = (float*)(lds + 16384);
  float* gArr  = (float*)(lds + 16896);
  float* bArr  = (float*)(lds + 17408);
  float* rowM  = (float*)(lds + 17920);
  float* rowIS = (float*)(lds + 18432);
  float* textL = (float*)(lds + 18944);   // [8][128]
  const float* scal = (const float*)(ws + OFF_SCAL);

  if (t < 128) {
    int idx = l * 512 + n0 + t;
    uArr[t] = ((const float*)(ws + OFF_U))[idx];
    gArr[t] = ((const float*)(ws + OFF_GG))[idx];
    bArr[t] = ((const float*)(ws + OFF_BB))[idx] + A.bias[l][n0 + t];
  } else {
    int r = t - 128;
    const float* st = (const float*)(ws + OFF_STAT) + (size_t)(l * 8192 + m0 + r) * 2;
    float s1 = st[0], s2 = st[1];
    float inv2C = 1.0f / (float)(2 * C);
    float mr = (s1 + scal[l]) * inv2C;
    float var = (s2 + scal[4 + l]) * inv2C - mr * mr;
    rowM[r] = mr;
    rowIS[r] = rsqrtf(var + 1e-5f);
  }
  {
    const float* tf = (const float*)(ws + OFF_TEXT);
#pragma unroll
    for (int i = 0; i < 4; ++i) {
      int idx = t + 256 * i;          // 0..1023 -> [8][128]
      textL[idx] = tf[(idx >> 7) * 512 + n0 + (idx & 127)];
    }
  }

  int w = t >> 6, lane = t & 63, quad = lane >> 4, lc = lane & 15;
  const char* Abf = ws + OFF_ABF + abf_off(l);
  const char* Bw  = ws + OFF_GWT + gwt_off(l);
  const char* aP[2]; const char* bP[2];
  char* aD[2]; char* bD[2];
#pragma unroll
  for (int i = 0; i < 2; ++i) {
    int li = i * 256 + t;
    int rr = li >> 2, kq = li & 3;
    aP[i] = Abf + ((size_t)(m0 + rr) * C + kq * 8) * 2;
    bP[i] = Bw  + ((size_t)(n0 + rr) * C + kq * 8) * 2;
    aD[i] = lds + i * 4096 + w * 1024;
    bD[i] = lds + 8192 + i * 4096 + w * 1024;
  }
  int wr = (w >> 1) * 64, wc = (w & 1) * 64;
  const char* aF = lds + (wr + lc) * 64 + quad * 16;
  const char* bF = lds + 8192 + (wc + lc) * 64 + quad * 16;

  f32x4 acc[4][4] = {};
  for (int k0 = 0; k0 < C; k0 += 32) {
    async_load16(aP[0], aD[0]); async_load16(aP[1], aD[1]);
    async_load16(bP[0], bD[0]); async_load16(bP[1], bD[1]);
    aP[0] += 64; aP[1] += 64; bP[0] += 64; bP[1] += 64;
    __syncthreads();
    bf16x8 av[4];
#pragma unroll
    for (int rt = 0; rt < 4; ++rt) av[rt] = *(const bf16x8*)(aF + rt * 1024);
#pragma unroll
    for (int ct = 0; ct < 4; ++ct) {
      bf16x8 bv = *(const bf16x8*)(bF + ct * 1024);
#pragma unroll
      for (int rt = 0; rt < 4; ++rt)
        acc[rt][ct] = __builtin_amdgcn_mfma_f32_16x16x32_bf16(av[rt], bv, acc[rt][ct], 0, 0, 0);
    }
    __syncthreads();
  }

  // epilogue: h = relu((acc + u - m*G)*invs + B); partial text dots + ||h||^2
  // slot = cb*2 + (w&1): this wave's col-half is private -> plain stores.
  int slot = cb * 2 + (w & 1);
#pragma unroll
  for (int rt = 0; rt < 4; ++rt) {
#pragma unroll
    for (int reg = 0; reg < 4; ++reg) {
      int ml = wr + rt * 16 + quad * 4 + reg;
      float rm = rowM[ml], ris = rowIS[ml];
      float p[9] = {};
#pragma unroll
      for (int ct = 0; ct < 4; ++ct) {
        int nl = wc + ct * 16 + lc;
        float h = fmaf(acc[rt][ct][reg] + uArr[nl] - rm * gArr[nl], ris, bArr[nl]);
        h = fmaxf(h, 0.f);
        p[8] = fmaf(h, h, p[8]);
#pragma unroll
        for (int k = 0; k < 8; ++k)
          p[k] = fmaf(h, textL[k * 128 + nl], p[k]);
      }
#pragma unroll
      for (int off = 1; off < 16; off <<= 1) {
#pragma unroll
        for (int k = 0; k < 9; ++k) p[k] += __shfl_xor(p[k], off);
      }
      if (lc == 0) {
        float* Lg = (float*)(ws + OFF_LOG) +
                    ((((size_t)l * 8192 + m0 + ml) * 8 + slot) << 4);
#pragma unroll
        for (int k = 0; k < 9; ++k) Lg[k] = p[k];
      }
    }
  }
}

// ================= finishK: reduce 8 slots + normalize + scale + softmax =================
__global__ __launch_bounds__(256) void finishK(const char* ws, const float* lsc,
                                               float* out) {
  int t = threadIdx.x;
  int row = blockIdx.x * 32 + (t >> 3), k = t & 7;
  float scale = fmaxf(lsc[0], 1e-4f) * 0.04419417382415922f;  // 1/sqrt(512)
  float x[4];
#pragma unroll
  for (int l = 0; l < 4; ++l) {
    const float* Lg = (const float*)(ws + OFF_LOG) + (((size_t)l * 8192 + row) << 7);
    float dot = 0.f, nsq = 0.f;
#pragma unroll
    for (int s = 0; s < 8; ++s) {
      dot += Lg[s * 16 + k];
      nsq += Lg[s * 16 + 8];
    }
    x[l] = dot * (scale / fmaxf(sqrtf(nsq), 1e-12f));
  }
  float mx = fmaxf(fmaxf(x[0], x[1]), fmaxf(x[2], x[3]));
  float e0 = __expf(x[0] - mx), e1 = __expf(x[1] - mx);
  float e2 = __expf(x[2] - mx), e3 = __expf(x[3] - mx);
  float inv = 1.0f / (e0 + e1 + e2 + e3);
  ((float4*)out)[(size_t)row * 8 + k] = make_float4(e0 * inv, e1 * inv, e2 * inv, e3 * inv);
}

extern "C" void kernel_launch(void* const* d_in, const int* in_sizes, int n_in,
                              void* d_out, int out_size, void* d_ws, size_t ws_size,
                              hipStream_t stream) {
  (void)n_in; (void)out_size;
  if (ws_size < (size_t)WS_TOTAL) return;  // loud failure: output stays poisoned
  char* ws = (char*)d_ws;
  bool dict = (in_sizes[1] == 64 * 256);
  PrepArgs pa;
  for (int l = 0; l < 4; ++l) {
    if (dict) {
      pa.pooled[l] = (const float*)d_in[6 * l + 0];
      pa.proto[l]  = (const float*)d_in[6 * l + 1];
      pa.g[l]      = (const float*)d_in[6 * l + 2];
      pa.beta[l]   = (const float*)d_in[6 * l + 3];
      pa.W[l]      = (const float*)d_in[6 * l + 4];
      pa.bias[l]   = (const float*)d_in[6 * l + 5];
    } else {
      pa.pooled[l] = (const float*)d_in[l];
      pa.proto[l]  = (const float*)d_in[4 + l];
      pa.g[l]      = (const float*)d_in[8 + l];
      pa.beta[l]   = (const float*)d_in[12 + l];
      pa.W[l]      = (const float*)d_in[16 + l];
      pa.bias[l]   = (const float*)d_in[20 + l];
    }
  }
  pa.text = (const float*)d_in[24];
  pa.lsc = (const float*)d_in[25];
  pa.ws = ws;

  // zero the atomic accumulators (U/GG/BB/SCAL; LOG needs no zeroing — all
  // slots are fully written by exactly one producer)
  hipMemsetAsync(ws + OFF_U, 0, 3 * 8192 + 256, stream);

  aconv<<<3840, 256, 0, stream>>>(pa);
  wtrans<<<481, 256, 0, stream>>>(pa);

  G2Args g2;
  g2.ws = ws;
  for (int l = 0; l < 4; ++l) g2.bias[l] = pa.bias[l];
  gemm2<<<1024, 256, 0, stream>>>(g2);
  finishK<<<256, 256, 0, stream>>>(ws, pa.lsc, (float*)d_out);
}

// Round 8
// 276.500 us; speedup vs baseline: 1.4733x; 1.1362x over previous
//
#include <hip/hip_runtime.h>
#include <stdint.h>

typedef __bf16 bf16x8 __attribute__((ext_vector_type(8)));
typedef float f32x4 __attribute__((ext_vector_type(4)));

// ---- workspace byte offsets ----
#define OFF_ABF   0u           // pooled as bf16, per level [8192][C]
#define OFF_GWT   62914560u    // (g*W)^T bf16 per level [512][C]
#define OFF_LOG   66846720u    // f32 [4][8192][8][16]: private partial slots (no atomics)
#define OFF_STAT  100401152u   // per (l,row): sum, sumsq  (4*8192*2 f32)
#define OFF_TEXT  100663296u   // 4096 f32 normalized text
#define OFF_U     100679680u   // 4*512 f32 (zeroed, atomic-accumulated)
#define OFF_GG    100687872u
#define OFF_BB    100696064u
#define OFF_SCAL  100704256u   // [0..3] sproto, [4..7] sqproto (zeroed)
#define WS_TOTAL  100719872u

__host__ __device__ __forceinline__ size_t abf_off(int l) {
  return (size_t)4194304u * (size_t)((1u << l) - 1u);
}
__host__ __device__ __forceinline__ size_t gwt_off(int l) {
  return (size_t)262144u * (size_t)((1u << l) - 1u);
}

__device__ __forceinline__ unsigned short f2bf(float x) {
  return (unsigned short)((__float_as_uint(x) + 0x8000u) >> 16);
}
__device__ __forceinline__ unsigned pack2(float a, float b) {
  return ((__float_as_uint(a) + 0x8000u) >> 16) |
         ((__float_as_uint(b) + 0x8000u) & 0xffff0000u);
}
__device__ __forceinline__ void async_load16(const void* g, void* l) {
  __builtin_amdgcn_global_load_lds((const __attribute__((address_space(1))) void*)g,
                                   (__attribute__((address_space(3))) void*)l,
                                   16, 0, 0);
}

struct PrepArgs {
  const float* pooled[4];
  const float* proto[4];
  const float* W[4];
  const float* g[4];
  const float* beta[4];
  const float* bias[4];
  const float* text;
  const float* lsc;
  char* ws;
};

// ================= aconv: one 8KB unit per wave, pure TLP (unchanged) =================
__device__ __forceinline__ void loadUnit(f32x4 (&buf)[8], const f32x4* base, int lane) {
#pragma unroll
  for (int i = 0; i < 4; ++i) {
    buf[2 * i]     = base[2 * (lane + 64 * i)];
    buf[2 * i + 1] = base[2 * (lane + 64 * i) + 1];
  }
}

template <int R>
__device__ __forceinline__ void procUnit(const f32x4 (&v)[8], char* Dst, float* st,
                                         int rowBase, int lane) {
  float p1[4], p2[4];
#pragma unroll
  for (int i = 0; i < 4; ++i) {
    f32x4 a = v[2 * i], b = v[2 * i + 1];
    float s1 = ((a[0] + a[1]) + (a[2] + a[3])) + ((b[0] + b[1]) + (b[2] + b[3]));
    float s2 = 0.f;
    s2 = fmaf(a[0], a[0], s2); s2 = fmaf(a[1], a[1], s2);
    s2 = fmaf(a[2], a[2], s2); s2 = fmaf(a[3], a[3], s2);
    s2 = fmaf(b[0], b[0], s2); s2 = fmaf(b[1], b[1], s2);
    s2 = fmaf(b[2], b[2], s2); s2 = fmaf(b[3], b[3], s2);
    p1[i] = s1; p2[i] = s2;
    uint4 o = make_uint4(pack2(a[0], a[1]), pack2(a[2], a[3]),
                         pack2(b[0], b[1]), pack2(b[2], b[3]));
    *(uint4*)(Dst + 16 * (size_t)(lane + 64 * i)) = o;
  }
  if constexpr (R == 1) {
    float s1 = (p1[0] + p1[1]) + (p1[2] + p1[3]);
    float s2 = (p2[0] + p2[1]) + (p2[2] + p2[3]);
#pragma unroll
    for (int off = 1; off < 64; off <<= 1) {
      s1 += __shfl_xor(s1, off); s2 += __shfl_xor(s2, off);
    }
    if (lane == 0) {
      st[2 * (size_t)rowBase] = s1; st[2 * (size_t)rowBase + 1] = s2;
    }
  } else if constexpr (R == 2) {
#pragma unroll
    for (int h = 0; h < 2; ++h) {
      float s1 = p1[2 * h] + p1[2 * h + 1], s2 = p2[2 * h] + p2[2 * h + 1];
#pragma unroll
      for (int off = 1; off < 64; off <<= 1) {
        s1 += __shfl_xor(s1, off); s2 += __shfl_xor(s2, off);
      }
      if (lane == 0) {
        st[2 * (size_t)(rowBase + h)] = s1; st[2 * (size_t)(rowBase + h) + 1] = s2;
      }
    }
  } else if constexpr (R == 4) {
#pragma unroll
    for (int i = 0; i < 4; ++i) {
      float s1 = p1[i], s2 = p2[i];
#pragma unroll
      for (int off = 1; off < 64; off <<= 1) {
        s1 += __shfl_xor(s1, off); s2 += __shfl_xor(s2, off);
      }
      if (lane == 0) {
        st[2 * (size_t)(rowBase + i)] = s1; st[2 * (size_t)(rowBase + i) + 1] = s2;
      }
    }
  } else {  // R == 8: lanes 0-31 hold row 2i, lanes 32-63 row 2i+1
#pragma unroll
    for (int i = 0; i < 4; ++i) {
      float s1 = p1[i], s2 = p2[i];
#pragma unroll
      for (int off = 1; off < 32; off <<= 1) {
        s1 += __shfl_xor(s1, off); s2 += __shfl_xor(s2, off);
      }
      if ((lane & 31) == 0) {
        int row = rowBase + 2 * i + (lane >> 5);
        st[2 * (size_t)row] = s1; st[2 * (size_t)row + 1] = s2;
      }
    }
  }
}

__global__ __launch_bounds__(256, 4) void aconv(PrepArgs A) {
  int t = threadIdx.x, bid = blockIdx.x;
  int w = t >> 6, lane = t & 63;
  // unit ids: l=3: [0,8192)  l=2: [8192,12288)  l=1: [12288,14336)  l=0: [14336,15360)
  int u0 = bid * 4 + w;   // ONE unit per wave
  int l, uL;
  if (u0 < 8192)       { l = 3; uL = u0; }
  else if (u0 < 12288) { l = 2; uL = u0 - 8192; }
  else if (u0 < 14336) { l = 1; uL = u0 - 12288; }
  else                 { l = 0; uL = u0 - 14336; }
  const f32x4* P = (const f32x4*)A.pooled[l] + (size_t)uL * 512;
  char* Dst = A.ws + OFF_ABF + abf_off(l) + (size_t)uL * 4096;
  float* st = (float*)(A.ws + OFF_STAT) + (size_t)l * 8192 * 2;
  f32x4 v[8];
  loadUnit(v, P, lane);
  if (l == 3)      procUnit<1>(v, Dst, st, uL,     lane);
  else if (l == 2) procUnit<2>(v, Dst, st, uL * 2, lane);
  else if (l == 1) procUnit<4>(v, Dst, st, uL * 4, lane);
  else             procUnit<8>(v, Dst, st, uL * 8, lane);
}

// ================= wtrans: W-slab transpose + Gsum/Bsum/u + pmean/scal + text =================
// 481 blocks: 480 W-slabs (64j x 128d) + 1 text-normalization block. (unchanged)
__global__ __launch_bounds__(256) void wtrans(PrepArgs A) {
  __shared__ unsigned short tile[128][66];     // padded: 2-way-only banking
  __shared__ float redG[4][128], redB[4][128], redU[4][128];
  __shared__ float gsh[64], bsh[64], psh[64];
  __shared__ float redP[4][64];
  int t = threadIdx.x, bid = blockIdx.x;

  if (bid == 480) {
    // ---- text l2norm: 8 rows x 512, 32 lanes/row ----
    int row = t >> 5, l32 = t & 31;
    const float* tr = A.text + row * 512 + l32;
    float v[16];
    float s = 0.f;
#pragma unroll
    for (int i = 0; i < 16; ++i) {
      v[i] = tr[32 * i];
      s = fmaf(v[i], v[i], s);
    }
#pragma unroll
    for (int off = 1; off < 32; off <<= 1) s += __shfl_xor(s, off);
    float inv = 1.0f / fmaxf(sqrtf(s), 1e-12f);
    float* tf = (float*)(A.ws + OFF_TEXT) + row * 512 + l32;
#pragma unroll
    for (int i = 0; i < 16; ++i) tf[32 * i] = v[i] * inv;
    return;
  }

  int l, idl;
  if (bid < 256)      { l = 3; idl = bid; }
  else if (bid < 384) { l = 2; idl = bid - 256; }
  else if (bid < 448) { l = 1; idl = bid - 384; }
  else                { l = 0; idl = bid - 448; }
  int C = 256 << l;
  int sid = idl >> 2, dchunk = idl & 3;
  int j0 = sid * 64, d0 = dchunk * 128;
  bool top = (j0 < C);
  int w = t >> 6, L = t & 63;
  float* scal = (float*)(A.ws + OFF_SCAL);

  if (t < 64) {
    gsh[t] = A.g[l][j0 + t];
    bsh[t] = A.beta[l][j0 + t];
  }
  if (!top) {
    const float* pr = A.proto[l];
    int cb0 = j0 - C;
    float s = 0.f;
#pragma unroll
    for (int r = 0; r < 16; ++r) s += pr[(size_t)(w * 16 + r) * C + cb0 + L];
    redP[w][L] = s;
  }
  __syncthreads();
  if (!top) {
    if (t < 64) {
      float pmv = (redP[0][t] + redP[1][t] + redP[2][t] + redP[3][t]) * (1.0f / 64.0f);
      psh[t] = pmv * gsh[t];
      if (dchunk == 0) {
        float s1 = pmv, s2 = pmv * pmv;
#pragma unroll
        for (int off = 1; off < 64; off <<= 1) {
          s1 += __shfl_xor(s1, off);
          s2 += __shfl_xor(s2, off);
        }
        if (t == 0) {
          atomicAdd(&scal[l], s1);
          atomicAdd(&scal[4 + l], s2);
        }
      }
    }
    __syncthreads();
  }

  const float* W = A.W[l];
  float2 v[16];
#pragma unroll
  for (int r = 0; r < 16; ++r) {
    int j = j0 + w * 16 + r;
    v[r] = *(const float2*)(W + (size_t)j * 512 + d0 + 2 * L);
  }
  float gp0 = 0.f, gp1 = 0.f, bp0 = 0.f, bp1 = 0.f, up0 = 0.f, up1 = 0.f;
#pragma unroll
  for (int r = 0; r < 16; ++r) {
    int jl = w * 16 + r;
    float g = gsh[jl], b = bsh[jl];
    gp0 = fmaf(g, v[r].x, gp0); gp1 = fmaf(g, v[r].y, gp1);
    bp0 = fmaf(b, v[r].x, bp0); bp1 = fmaf(b, v[r].y, bp1);
    if (top) {
      tile[2 * L][jl] = f2bf(g * v[r].x);
      tile[2 * L + 1][jl] = f2bf(g * v[r].y);
    } else {
      float p = psh[jl];
      up0 = fmaf(p, v[r].x, up0); up1 = fmaf(p, v[r].y, up1);
    }
  }
  redG[w][2 * L] = gp0; redG[w][2 * L + 1] = gp1;
  redB[w][2 * L] = bp0; redB[w][2 * L + 1] = bp1;
  if (!top) { redU[w][2 * L] = up0; redU[w][2 * L + 1] = up1; }
  __syncthreads();

  if (t < 128) {
    int d = l * 512 + d0 + t;
    float G = redG[0][t] + redG[1][t] + redG[2][t] + redG[3][t];
    float B = redB[0][t] + redB[1][t] + redB[2][t] + redB[3][t];
    atomicAdd(&((float*)(A.ws + OFF_GG))[d], G);
    atomicAdd(&((float*)(A.ws + OFF_BB))[d], B);
    if (!top) {
      float U = redU[0][t] + redU[1][t] + redU[2][t] + redU[3][t];
      atomicAdd(&((float*)(A.ws + OFF_U))[d], U);
    }
  }
  if (top) {
    unsigned short* gwT = (unsigned short*)(A.ws + OFF_GWT + gwt_off(l));
    int d = t >> 1, jh = (t & 1) * 32;
    const unsigned* trow = (const unsigned*)&tile[d][jh];  // 4B-aligned
    uint4 q0 = make_uint4(trow[0], trow[1], trow[2], trow[3]);
    uint4 q1 = make_uint4(trow[4], trow[5], trow[6], trow[7]);
    uint4 q2 = make_uint4(trow[8], trow[9], trow[10], trow[11]);
    uint4 q3 = make_uint4(trow[12], trow[13], trow[14], trow[15]);
    uint4* dst = (uint4*)(gwT + (size_t)(d0 + d) * C + j0 + jh);
    dst[0] = q0; dst[1] = q1; dst[2] = q2; dst[3] = q3;
  }
}

// ================= gemm2: R2 core + BALANCED XCD swizzle + fused epilogue =================
// R7 lesson: the chunked swizzle bid=(blk&7)*128+(blk>>3) gave XCD0/1 all of
// l=3 (64 ksteps/block) and XCD6/7 all of l=0 (8 ksteps) — 2.13x work imbalance
// = the entire 118-vs-66us gap (MFMA-cycles were identical to R2).
// Balanced mapping: XCD x gets 32 blocks of EACH level (3840 block-ksteps, the
// exact mean); cb-siblings stay adjacent for A-panel L2 reuse; each level's B
// panel is reused by the XCD's 32 blocks. Active L2 set ~3 A-panels + 1 B < 4MB.
struct G2Args {
  char* ws;
  const float* bias[4];
};

__global__ __launch_bounds__(256, 3) void gemm2(G2Args A) {
  __shared__ __align__(16) char lds[23040];
  char* ws = A.ws;
  int t = threadIdx.x;
  int xcd = blockIdx.x & 7;        // round-robin XCD assumption (perf-only)
  int j   = blockIdx.x >> 3;       // 0..127 within this XCD's share
  int l   = 3 - (j >> 5);          // 32 blocks of each level per XCD
  int jj  = j & 31;
  int rb  = xcd * 8 + (jj >> 2);
  int cb  = jj & 3;
  int C = 256 << l;
  int m0 = rb * 128, n0 = cb * 128;

  float* uArr  = (float*)(lds + 16384);
  float* gArr  = (float*)(lds + 16896);
  float* bArr  = (float*)(lds + 17408);
  float* rowM  = (float*)(lds + 17920);
  float* rowIS = (float*)(lds + 18432);
  float* textL = (float*)(lds + 18944);   // [8][128]
  const float* scal = (const float*)(ws + OFF_SCAL);

  if (t < 128) {
    int idx = l * 512 + n0 + t;
    uArr[t] = ((const float*)(ws + OFF_U))[idx];
    gArr[t] = ((const float*)(ws + OFF_GG))[idx];
    bArr[t] = ((const float*)(ws + OFF_BB))[idx] + A.bias[l][n0 + t];
  } else {
    int r = t - 128;
    const float* st = (const float*)(ws + OFF_STAT) + (size_t)(l * 8192 + m0 + r) * 2;
    float s1 = st[0], s2 = st[1];
    float inv2C = 1.0f / (float)(2 * C);
    float mr = (s1 + scal[l]) * inv2C;
    float var = (s2 + scal[4 + l]) * inv2C - mr * mr;
    rowM[r] = mr;
    rowIS[r] = rsqrtf(var + 1e-5f);
  }
  {
    const float* tf = (const float*)(ws + OFF_TEXT);
#pragma unroll
    for (int i = 0; i < 4; ++i) {
      int idx = t + 256 * i;          // 0..1023 -> [8][128]
      textL[idx] = tf[(idx >> 7) * 512 + n0 + (idx & 127)];
    }
  }

  int w = t >> 6, lane = t & 63, quad = lane >> 4, lc = lane & 15;
  const char* Abf = ws + OFF_ABF + abf_off(l);
  const char* Bw  = ws + OFF_GWT + gwt_off(l);
  const char* aP[2]; const char* bP[2];
  char* aD[2]; char* bD[2];
#pragma unroll
  for (int i = 0; i < 2; ++i) {
    int li = i * 256 + t;
    int rr = li >> 2, kq = li & 3;
    aP[i] = Abf + ((size_t)(m0 + rr) * C + kq * 8) * 2;
    bP[i] = Bw  + ((size_t)(n0 + rr) * C + kq * 8) * 2;
    aD[i] = lds + i * 4096 + w * 1024;
    bD[i] = lds + 8192 + i * 4096 + w * 1024;
  }
  int wr = (w >> 1) * 64, wc = (w & 1) * 64;
  const char* aF = lds + (wr + lc) * 64 + quad * 16;
  const char* bF = lds + 8192 + (wc + lc) * 64 + quad * 16;

  f32x4 acc[4][4] = {};
  for (int k0 = 0; k0 < C; k0 += 32) {
    async_load16(aP[0], aD[0]); async_load16(aP[1], aD[1]);
    async_load16(bP[0], bD[0]); async_load16(bP[1], bD[1]);
    aP[0] += 64; aP[1] += 64; bP[0] += 64; bP[1] += 64;
    __syncthreads();
    bf16x8 av[4];
#pragma unroll
    for (int rt = 0; rt < 4; ++rt) av[rt] = *(const bf16x8*)(aF + rt * 1024);
#pragma unroll
    for (int ct = 0; ct < 4; ++ct) {
      bf16x8 bv = *(const bf16x8*)(bF + ct * 1024);
#pragma unroll
      for (int rt = 0; rt < 4; ++rt)
        acc[rt][ct] = __builtin_amdgcn_mfma_f32_16x16x32_bf16(av[rt], bv, acc[rt][ct], 0, 0, 0);
    }
    __syncthreads();
  }

  // epilogue: h = relu((acc + u - m*G)*invs + B); partial text dots + ||h||^2
  // slot = cb*2 + (w&1): this wave's col-half is private -> plain stores.
  int slot = cb * 2 + (w & 1);
#pragma unroll
  for (int rt = 0; rt < 4; ++rt) {
#pragma unroll
    for (int reg = 0; reg < 4; ++reg) {
      int ml = wr + rt * 16 + quad * 4 + reg;
      float rm = rowM[ml], ris = rowIS[ml];
      float p[9] = {};
#pragma unroll
      for (int ct = 0; ct < 4; ++ct) {
        int nl = wc + ct * 16 + lc;
        float h = fmaf(acc[rt][ct][reg] + uArr[nl] - rm * gArr[nl], ris, bArr[nl]);
        h = fmaxf(h, 0.f);
        p[8] = fmaf(h, h, p[8]);
#pragma unroll
        for (int k = 0; k < 8; ++k)
          p[k] = fmaf(h, textL[k * 128 + nl], p[k]);
      }
#pragma unroll
      for (int off = 1; off < 16; off <<= 1) {
#pragma unroll
        for (int k = 0; k < 9; ++k) p[k] += __shfl_xor(p[k], off);
      }
      if (lc == 0) {
        float* Lg = (float*)(ws + OFF_LOG) +
                    ((((size_t)l * 8192 + m0 + ml) * 8 + slot) << 4);
#pragma unroll
        for (int k = 0; k < 9; ++k) Lg[k] = p[k];
      }
    }
  }
}

// ================= finishK: reduce 8 slots + normalize + scale + softmax =================
__global__ __launch_bounds__(256) void finishK(const char* ws, const float* lsc,
                                               float* out) {
  int t = threadIdx.x;
  int row = blockIdx.x * 32 + (t >> 3), k = t & 7;
  float scale = fmaxf(lsc[0], 1e-4f) * 0.04419417382415922f;  // 1/sqrt(512)
  float x[4];
#pragma unroll
  for (int l = 0; l < 4; ++l) {
    const float* Lg = (const float*)(ws + OFF_LOG) + (((size_t)l * 8192 + row) << 7);
    float dot = 0.f, nsq = 0.f;
#pragma unroll
    for (int s = 0; s < 8; ++s) {
      dot += Lg[s * 16 + k];
      nsq += Lg[s * 16 + 8];
    }
    x[l] = dot * (scale / fmaxf(sqrtf(nsq), 1e-12f));
  }
  float mx = fmaxf(fmaxf(x[0], x[1]), fmaxf(x[2], x[3]));
  float e0 = __expf(x[0] - mx), e1 = __expf(x[1] - mx);
  float e2 = __expf(x[2] - mx), e3 = __expf(x[3] - mx);
  float inv = 1.0f / (e0 + e1 + e2 + e3);
  ((float4*)out)[(size_t)row * 8 + k] = make_float4(e0 * inv, e1 * inv, e2 * inv, e3 * inv);
}

extern "C" void kernel_launch(void* const* d_in, const int* in_sizes, int n_in,
                              void* d_out, int out_size, void* d_ws, size_t ws_size,
                              hipStream_t stream) {
  (void)n_in; (void)out_size;
  if (ws_size < (size_t)WS_TOTAL) return;  // loud failure: output stays poisoned
  char* ws = (char*)d_ws;
  bool dict = (in_sizes[1] == 64 * 256);
  PrepArgs pa;
  for (int l = 0; l < 4; ++l) {
    if (dict) {
      pa.pooled[l] = (const float*)d_in[6 * l + 0];
      pa.proto[l]  = (const float*)d_in[6 * l + 1];
      pa.g[l]      = (const float*)d_in[6 * l + 2];
      pa.beta[l]   = (const float*)d_in[6 * l + 3];
      pa.W[l]      = (const float*)d_in[6 * l + 4];
      pa.bias[l]   = (const float*)d_in[6 * l + 5];
    } else {
      pa.pooled[l] = (const float*)d_in[l];
      pa.proto[l]  = (const float*)d_in[4 + l];
      pa.g[l]      = (const float*)d_in[8 + l];
      pa.beta[l]   = (const float*)d_in[12 + l];
      pa.W[l]      = (const float*)d_in[16 + l];
      pa.bias[l]   = (const float*)d_in[20 + l];
    }
  }
  pa.text = (const float*)d_in[24];
  pa.lsc = (const float*)d_in[25];
  pa.ws = ws;

  // zero the atomic accumulators (U/GG/BB/SCAL; LOG needs no zeroing — all
  // slots are fully written by exactly one producer)
  hipMemsetAsync(ws + OFF_U, 0, 3 * 8192 + 256, stream);

  aconv<<<3840, 256, 0, stream>>>(pa);
  wtrans<<<481, 256, 0, stream>>>(pa);

  G2Args g2;
  g2.ws = ws;
  for (int l = 0; l < 4; ++l) g2.bias[l] = pa.bias[l];
  gemm2<<<1024, 256, 0, stream>>>(g2);
  finishK<<<256, 256, 0, stream>>>(ws, pa.lsc, (float*)d_out);
}

// Round 9
// 276.179 us; speedup vs baseline: 1.4750x; 1.0012x over previous
//
#include <hip/hip_runtime.h>
#include <stdint.h>

typedef __bf16 bf16x8 __attribute__((ext_vector_type(8)));
typedef float f32x4 __attribute__((ext_vector_type(4)));

// ---- workspace byte offsets ----
#define OFF_ABF   0u           // pooled as bf16, per level [8192][C]
#define OFF_GWT   62914560u    // (g*W)^T bf16 per level [512][C]
#define OFF_LOG   66846720u    // f32 [4][8192][8][16]: private partial slots (no atomics)
#define OFF_STAT  100401152u   // per (l,row): sum, sumsq  (4*8192*2 f32)
#define OFF_TEXT  100663296u   // 4096 f32 normalized text
#define OFF_U     100679680u   // 4*512 f32 (zeroed, atomic-accumulated)
#define OFF_GG    100687872u
#define OFF_BB    100696064u
#define OFF_SCAL  100704256u   // [0..3] sproto, [4..7] sqproto (zeroed)
#define WS_TOTAL  100719872u

__host__ __device__ __forceinline__ size_t abf_off(int l) {
  return (size_t)4194304u * (size_t)((1u << l) - 1u);
}
__host__ __device__ __forceinline__ size_t gwt_off(int l) {
  return (size_t)262144u * (size_t)((1u << l) - 1u);
}

__device__ __forceinline__ unsigned short f2bf(float x) {
  return (unsigned short)((__float_as_uint(x) + 0x8000u) >> 16);
}
__device__ __forceinline__ unsigned pack2(float a, float b) {
  return ((__float_as_uint(a) + 0x8000u) >> 16) |
         ((__float_as_uint(b) + 0x8000u) & 0xffff0000u);
}
__device__ __forceinline__ void async_load16(const void* g, void* l) {
  __builtin_amdgcn_global_load_lds((const __attribute__((address_space(1))) void*)g,
                                   (__attribute__((address_space(3))) void*)l,
                                   16, 0, 0);
}

struct PrepArgs {
  const float* pooled[4];
  const float* proto[4];
  const float* W[4];
  const float* g[4];
  const float* beta[4];
  const float* bias[4];
  const float* text;
  const float* lsc;
  char* ws;
};

// ---------------- aconv helpers: one 8KB unit per wave, pure TLP ----------------
__device__ __forceinline__ void loadUnit(f32x4 (&buf)[8], const f32x4* base, int lane) {
#pragma unroll
  for (int i = 0; i < 4; ++i) {
    buf[2 * i]     = base[2 * (lane + 64 * i)];
    buf[2 * i + 1] = base[2 * (lane + 64 * i) + 1];
  }
}

template <int R>
__device__ __forceinline__ void procUnit(const f32x4 (&v)[8], char* Dst, float* st,
                                         int rowBase, int lane) {
  float p1[4], p2[4];
#pragma unroll
  for (int i = 0; i < 4; ++i) {
    f32x4 a = v[2 * i], b = v[2 * i + 1];
    float s1 = ((a[0] + a[1]) + (a[2] + a[3])) + ((b[0] + b[1]) + (b[2] + b[3]));
    float s2 = 0.f;
    s2 = fmaf(a[0], a[0], s2); s2 = fmaf(a[1], a[1], s2);
    s2 = fmaf(a[2], a[2], s2); s2 = fmaf(a[3], a[3], s2);
    s2 = fmaf(b[0], b[0], s2); s2 = fmaf(b[1], b[1], s2);
    s2 = fmaf(b[2], b[2], s2); s2 = fmaf(b[3], b[3], s2);
    p1[i] = s1; p2[i] = s2;
    uint4 o = make_uint4(pack2(a[0], a[1]), pack2(a[2], a[3]),
                         pack2(b[0], b[1]), pack2(b[2], b[3]));
    *(uint4*)(Dst + 16 * (size_t)(lane + 64 * i)) = o;
  }
  if constexpr (R == 1) {
    float s1 = (p1[0] + p1[1]) + (p1[2] + p1[3]);
    float s2 = (p2[0] + p2[1]) + (p2[2] + p2[3]);
#pragma unroll
    for (int off = 1; off < 64; off <<= 1) {
      s1 += __shfl_xor(s1, off); s2 += __shfl_xor(s2, off);
    }
    if (lane == 0) {
      st[2 * (size_t)rowBase] = s1; st[2 * (size_t)rowBase + 1] = s2;
    }
  } else if constexpr (R == 2) {
#pragma unroll
    for (int h = 0; h < 2; ++h) {
      float s1 = p1[2 * h] + p1[2 * h + 1], s2 = p2[2 * h] + p2[2 * h + 1];
#pragma unroll
      for (int off = 1; off < 64; off <<= 1) {
        s1 += __shfl_xor(s1, off); s2 += __shfl_xor(s2, off);
      }
      if (lane == 0) {
        st[2 * (size_t)(rowBase + h)] = s1; st[2 * (size_t)(rowBase + h) + 1] = s2;
      }
    }
  } else if constexpr (R == 4) {
#pragma unroll
    for (int i = 0; i < 4; ++i) {
      float s1 = p1[i], s2 = p2[i];
#pragma unroll
      for (int off = 1; off < 64; off <<= 1) {
        s1 += __shfl_xor(s1, off); s2 += __shfl_xor(s2, off);
      }
      if (lane == 0) {
        st[2 * (size_t)(rowBase + i)] = s1; st[2 * (size_t)(rowBase + i) + 1] = s2;
      }
    }
  } else {  // R == 8: lanes 0-31 hold row 2i, lanes 32-63 row 2i+1
#pragma unroll
    for (int i = 0; i < 4; ++i) {
      float s1 = p1[i], s2 = p2[i];
#pragma unroll
      for (int off = 1; off < 32; off <<= 1) {
        s1 += __shfl_xor(s1, off); s2 += __shfl_xor(s2, off);
      }
      if ((lane & 31) == 0) {
        int row = rowBase + 2 * i + (lane >> 5);
        st[2 * (size_t)row] = s1; st[2 * (size_t)row + 1] = s2;
      }
    }
  }
}

// ================= prep: wtrans (bids 0..480) + aconv (bids 481..4320) merged ====
// The two phases are independent (read inputs, write disjoint ws regions).
// Merging overlaps wtrans under aconv's memory-bound tail and drops one launch.
// wtrans blocks go first so they start early; divergence is block-level only.
__global__ __launch_bounds__(256, 4) void prep(PrepArgs A) {
  __shared__ unsigned short tile[128][66];     // padded: 2-way-only banking
  __shared__ float redG[4][128], redB[4][128], redU[4][128];
  __shared__ float gsh[64], bsh[64], psh[64];
  __shared__ float redP[4][64];
  int t = threadIdx.x, bid = blockIdx.x;
  int w = t >> 6, lane = t & 63;

  if (bid >= 481) {
    // ---------------- aconv path ----------------
    int u0 = (bid - 481) * 4 + w;   // ONE 8KB unit per wave
    int l, uL;
    if (u0 < 8192)       { l = 3; uL = u0; }
    else if (u0 < 12288) { l = 2; uL = u0 - 8192; }
    else if (u0 < 14336) { l = 1; uL = u0 - 12288; }
    else                 { l = 0; uL = u0 - 14336; }
    const f32x4* P = (const f32x4*)A.pooled[l] + (size_t)uL * 512;
    char* Dst = A.ws + OFF_ABF + abf_off(l) + (size_t)uL * 4096;
    float* st = (float*)(A.ws + OFF_STAT) + (size_t)l * 8192 * 2;
    f32x4 v[8];
    loadUnit(v, P, lane);
    if (l == 3)      procUnit<1>(v, Dst, st, uL,     lane);
    else if (l == 2) procUnit<2>(v, Dst, st, uL * 2, lane);
    else if (l == 1) procUnit<4>(v, Dst, st, uL * 4, lane);
    else             procUnit<8>(v, Dst, st, uL * 8, lane);
    return;
  }

  if (bid == 480) {
    // ---- text l2norm: 8 rows x 512, 32 lanes/row ----
    int row = t >> 5, l32 = t & 31;
    const float* tr = A.text + row * 512 + l32;
    float v[16];
    float s = 0.f;
#pragma unroll
    for (int i = 0; i < 16; ++i) {
      v[i] = tr[32 * i];
      s = fmaf(v[i], v[i], s);
    }
#pragma unroll
    for (int off = 1; off < 32; off <<= 1) s += __shfl_xor(s, off);
    float inv = 1.0f / fmaxf(sqrtf(s), 1e-12f);
    float* tf = (float*)(A.ws + OFF_TEXT) + row * 512 + l32;
#pragma unroll
    for (int i = 0; i < 16; ++i) tf[32 * i] = v[i] * inv;
    return;
  }

  // ---------------- wtrans path (bids 0..479) ----------------
  int l, idl;
  if (bid < 256)      { l = 3; idl = bid; }
  else if (bid < 384) { l = 2; idl = bid - 256; }
  else if (bid < 448) { l = 1; idl = bid - 384; }
  else                { l = 0; idl = bid - 448; }
  int C = 256 << l;
  int sid = idl >> 2, dchunk = idl & 3;
  int j0 = sid * 64, d0 = dchunk * 128;
  bool top = (j0 < C);
  int L = lane;
  float* scal = (float*)(A.ws + OFF_SCAL);

  if (t < 64) {
    gsh[t] = A.g[l][j0 + t];
    bsh[t] = A.beta[l][j0 + t];
  }
  if (!top) {
    const float* pr = A.proto[l];
    int cb0 = j0 - C;
    float s = 0.f;
#pragma unroll
    for (int r = 0; r < 16; ++r) s += pr[(size_t)(w * 16 + r) * C + cb0 + L];
    redP[w][L] = s;
  }
  __syncthreads();
  if (!top) {
    if (t < 64) {
      float pmv = (redP[0][t] + redP[1][t] + redP[2][t] + redP[3][t]) * (1.0f / 64.0f);
      psh[t] = pmv * gsh[t];
      if (dchunk == 0) {
        float s1 = pmv, s2 = pmv * pmv;
#pragma unroll
        for (int off = 1; off < 64; off <<= 1) {
          s1 += __shfl_xor(s1, off);
          s2 += __shfl_xor(s2, off);
        }
        if (t == 0) {
          atomicAdd(&scal[l], s1);
          atomicAdd(&scal[4 + l], s2);
        }
      }
    }
    __syncthreads();
  }

  const float* W = A.W[l];
  float2 v[16];
#pragma unroll
  for (int r = 0; r < 16; ++r) {
    int j = j0 + w * 16 + r;
    v[r] = *(const float2*)(W + (size_t)j * 512 + d0 + 2 * L);
  }
  float gp0 = 0.f, gp1 = 0.f, bp0 = 0.f, bp1 = 0.f, up0 = 0.f, up1 = 0.f;
#pragma unroll
  for (int r = 0; r < 16; ++r) {
    int jl = w * 16 + r;
    float g = gsh[jl], b = bsh[jl];
    gp0 = fmaf(g, v[r].x, gp0); gp1 = fmaf(g, v[r].y, gp1);
    bp0 = fmaf(b, v[r].x, bp0); bp1 = fmaf(b, v[r].y, bp1);
    if (top) {
      tile[2 * L][jl] = f2bf(g * v[r].x);
      tile[2 * L + 1][jl] = f2bf(g * v[r].y);
    } else {
      float p = psh[jl];
      up0 = fmaf(p, v[r].x, up0); up1 = fmaf(p, v[r].y, up1);
    }
  }
  redG[w][2 * L] = gp0; redG[w][2 * L + 1] = gp1;
  redB[w][2 * L] = bp0; redB[w][2 * L + 1] = bp1;
  if (!top) { redU[w][2 * L] = up0; redU[w][2 * L + 1] = up1; }
  __syncthreads();

  if (t < 128) {
    int d = l * 512 + d0 + t;
    float G = redG[0][t] + redG[1][t] + redG[2][t] + redG[3][t];
    float B = redB[0][t] + redB[1][t] + redB[2][t] + redB[3][t];
    atomicAdd(&((float*)(A.ws + OFF_GG))[d], G);
    atomicAdd(&((float*)(A.ws + OFF_BB))[d], B);
    if (!top) {
      float U = redU[0][t] + redU[1][t] + redU[2][t] + redU[3][t];
      atomicAdd(&((float*)(A.ws + OFF_U))[d], U);
    }
  }
  if (top) {
    unsigned short* gwT = (unsigned short*)(A.ws + OFF_GWT + gwt_off(l));
    int d = t >> 1, jh = (t & 1) * 32;
    const unsigned* trow = (const unsigned*)&tile[d][jh];  // 4B-aligned
    uint4 q0 = make_uint4(trow[0], trow[1], trow[2], trow[3]);
    uint4 q1 = make_uint4(trow[4], trow[5], trow[6], trow[7]);
    uint4 q2 = make_uint4(trow[8], trow[9], trow[10], trow[11]);
    uint4 q3 = make_uint4(trow[12], trow[13], trow[14], trow[15]);
    uint4* dst = (uint4*)(gwT + (size_t)(d0 + d) * C + j0 + jh);
    dst[0] = q0; dst[1] = q1; dst[2] = q2; dst[3] = q3;
  }
}

// ================= gemm2: balanced-XCD core + granule-swizzled LDS + fused epilogue ==
// R8 lesson: fragment reads row*64 + quad*16 put 16 lanes on 2 bank-starts ->
// 8-way ds_read conflict (3.93M/dispatch all session). Fix (rule #21, both
// sides): DMA SOURCE granule = kq ^ ((row>>1)&3) with linear LDS dest; read
// slot = quad ^ ((row>>1)&3). row+16 preserves (row>>1)&3, so the per-lane XOR
// is constant across rt/ct tiles. Spread = 8 bank-starts x2 = 2-way = free.
struct G2Args {
  char* ws;
  const float* bias[4];
};

__global__ __launch_bounds__(256, 3) void gemm2(G2Args A) {
  __shared__ __align__(16) char lds[23040];
  char* ws = A.ws;
  int t = threadIdx.x;
  int xcd = blockIdx.x & 7;        // round-robin XCD assumption (perf-only)
  int j   = blockIdx.x >> 3;       // 0..127 within this XCD's share
  int l   = 3 - (j >> 5);          // 32 blocks of each level per XCD (balanced)
  int jj  = j & 31;
  int rb  = xcd * 8 + (jj >> 2);
  int cb  = jj & 3;
  int C = 256 << l;
  int m0 = rb * 128, n0 = cb * 128;

  float* uArr  = (float*)(lds + 16384);
  float* gArr  = (float*)(lds + 16896);
  float* bArr  = (float*)(lds + 17408);
  float* rowM  = (float*)(lds + 17920);
  float* rowIS = (float*)(lds + 18432);
  float* textL = (float*)(lds + 18944);   // [8][128]
  const float* scal = (const float*)(ws + OFF_SCAL);

  if (t < 128) {
    int idx = l * 512 + n0 + t;
    uArr[t] = ((const float*)(ws + OFF_U))[idx];
    gArr[t] = ((const float*)(ws + OFF_GG))[idx];
    bArr[t] = ((const float*)(ws + OFF_BB))[idx] + A.bias[l][n0 + t];
  } else {
    int r = t - 128;
    const float* st = (const float*)(ws + OFF_STAT) + (size_t)(l * 8192 + m0 + r) * 2;
    float s1 = st[0], s2 = st[1];
    float inv2C = 1.0f / (float)(2 * C);
    float mr = (s1 + scal[l]) * inv2C;
    float var = (s2 + scal[4 + l]) * inv2C - mr * mr;
    rowM[r] = mr;
    rowIS[r] = rsqrtf(var + 1e-5f);
  }
  {
    const float* tf = (const float*)(ws + OFF_TEXT);
#pragma unroll
    for (int i = 0; i < 4; ++i) {
      int idx = t + 256 * i;          // 0..1023 -> [8][128]
      textL[idx] = tf[(idx >> 7) * 512 + n0 + (idx & 127)];
    }
  }

  int w = t >> 6, lane = t & 63, quad = lane >> 4, lc = lane & 15;
  const char* Abf = ws + OFF_ABF + abf_off(l);
  const char* Bw  = ws + OFF_GWT + gwt_off(l);
  const char* aP[2]; const char* bP[2];
  char* aD[2]; char* bD[2];
#pragma unroll
  for (int i = 0; i < 2; ++i) {
    int li = i * 256 + t;
    int rr = li >> 2, kq = li & 3;
    int sw = kq ^ ((rr >> 1) & 3);          // pre-swizzled source granule
    aP[i] = Abf + ((size_t)(m0 + rr) * C + sw * 8) * 2;
    bP[i] = Bw  + ((size_t)(n0 + rr) * C + sw * 8) * 2;
    aD[i] = lds + i * 4096 + w * 1024;
    bD[i] = lds + 8192 + i * 4096 + w * 1024;
  }
  int wr = (w >> 1) * 64, wc = (w & 1) * 64;
  int arow = wr + lc, brow = wc + lc;
  const char* aF = lds + arow * 64 + (quad ^ ((arow >> 1) & 3)) * 16;
  const char* bF = lds + 8192 + brow * 64 + (quad ^ ((brow >> 1) & 3)) * 16;

  f32x4 acc[4][4] = {};
  for (int k0 = 0; k0 < C; k0 += 32) {
    async_load16(aP[0], aD[0]); async_load16(aP[1], aD[1]);
    async_load16(bP[0], bD[0]); async_load16(bP[1], bD[1]);
    aP[0] += 64; aP[1] += 64; bP[0] += 64; bP[1] += 64;
    __syncthreads();
    bf16x8 av[4];
#pragma unroll
    for (int rt = 0; rt < 4; ++rt) av[rt] = *(const bf16x8*)(aF + rt * 1024);
#pragma unroll
    for (int ct = 0; ct < 4; ++ct) {
      bf16x8 bv = *(const bf16x8*)(bF + ct * 1024);
#pragma unroll
      for (int rt = 0; rt < 4; ++rt)
        acc[rt][ct] = __builtin_amdgcn_mfma_f32_16x16x32_bf16(av[rt], bv, acc[rt][ct], 0, 0, 0);
    }
    __syncthreads();
  }

  // epilogue: h = relu((acc + u - m*G)*invs + B); partial text dots + ||h||^2
  // slot = cb*2 + (w&1): this wave's col-half is private -> plain stores.
  int slot = cb * 2 + (w & 1);
#pragma unroll
  for (int rt = 0; rt < 4; ++rt) {
#pragma unroll
    for (int reg = 0; reg < 4; ++reg) {
      int ml = wr + rt * 16 + quad * 4 + reg;
      float rm = rowM[ml], ris = rowIS[ml];
      float p[9] = {};
#pragma unroll
      for (int ct = 0; ct < 4; ++ct) {
        int nl = wc + ct * 16 + lc;
        float h = fmaf(acc[rt][ct][reg] + uArr[nl] - rm * gArr[nl], ris, bArr[nl]);
        h = fmaxf(h, 0.f);
        p[8] = fmaf(h, h, p[8]);
#pragma unroll
        for (int k = 0; k < 8; ++k)
          p[k] = fmaf(h, textL[k * 128 + nl], p[k]);
      }
#pragma unroll
      for (int off = 1; off < 16; off <<= 1) {
#pragma unroll
        for (int k = 0; k < 9; ++k) p[k] += __shfl_xor(p[k], off);
      }
      if (lc == 0) {
        float* Lg = (float*)(ws + OFF_LOG) +
                    ((((size_t)l * 8192 + m0 + ml) * 8 + slot) << 4);
#pragma unroll
        for (int k = 0; k < 9; ++k) Lg[k] = p[k];
      }
    }
  }
}

// ================= finishK: reduce 8 slots + normalize + scale + softmax =================
__global__ __launch_bounds__(256) void finishK(const char* ws, const float* lsc,
                                               float* out) {
  int t = threadIdx.x;
  int row = blockIdx.x * 32 + (t >> 3), k = t & 7;
  float scale = fmaxf(lsc[0], 1e-4f) * 0.04419417382415922f;  // 1/sqrt(512)
  float x[4];
#pragma unroll
  for (int l = 0; l < 4; ++l) {
    const float* Lg = (const float*)(ws + OFF_LOG) + (((size_t)l * 8192 + row) << 7);
    float dot = 0.f, nsq = 0.f;
#pragma unroll
    for (int s = 0; s < 8; ++s) {
      dot += Lg[s * 16 + k];
      nsq += Lg[s * 16 + 8];
    }
    x[l] = dot * (scale / fmaxf(sqrtf(nsq), 1e-12f));
  }
  float mx = fmaxf(fmaxf(x[0], x[1]), fmaxf(x[2], x[3]));
  float e0 = __expf(x[0] - mx), e1 = __expf(x[1] - mx);
  float e2 = __expf(x[2] - mx), e3 = __expf(x[3] - mx);
  float inv = 1.0f / (e0 + e1 + e2 + e3);
  ((float4*)out)[(size_t)row * 8 + k] = make_float4(e0 * inv, e1 * inv, e2 * inv, e3 * inv);
}

extern "C" void kernel_launch(void* const* d_in, const int* in_sizes, int n_in,
                              void* d_out, int out_size, void* d_ws, size_t ws_size,
                              hipStream_t stream) {
  (void)n_in; (void)out_size;
  if (ws_size < (size_t)WS_TOTAL) return;  // loud failure: output stays poisoned
  char* ws = (char*)d_ws;
  bool dict = (in_sizes[1] == 64 * 256);
  PrepArgs pa;
  for (int l = 0; l < 4; ++l) {
    if (dict) {
      pa.pooled[l] = (const float*)d_in[6 * l + 0];
      pa.proto[l]  = (const float*)d_in[6 * l + 1];
      pa.g[l]      = (const float*)d_in[6 * l + 2];
      pa.beta[l]   = (const float*)d_in[6 * l + 3];
      pa.W[l]      = (const float*)d_in[6 * l + 4];
      pa.bias[l]   = (const float*)d_in[6 * l + 5];
    } else {
      pa.pooled[l] = (const float*)d_in[l];
      pa.proto[l]  = (const float*)d_in[4 + l];
      pa.g[l]      = (const float*)d_in[8 + l];
      pa.beta[l]   = (const float*)d_in[12 + l];
      pa.W[l]      = (const float*)d_in[16 + l];
      pa.bias[l]   = (const float*)d_in[20 + l];
    }
  }
  pa.text = (const float*)d_in[24];
  pa.lsc = (const float*)d_in[25];
  pa.ws = ws;

  // zero the atomic accumulators (U/GG/BB/SCAL; LOG needs no zeroing — all
  // slots are fully written by exactly one producer)
  hipMemsetAsync(ws + OFF_U, 0, 3 * 8192 + 256, stream);

  prep<<<4321, 256, 0, stream>>>(pa);

  G2Args g2;
  g2.ws = ws;
  for (int l = 0; l < 4; ++l) g2.bias[l] = pa.bias[l];
  gemm2<<<1024, 256, 0, stream>>>(g2);
  finishK<<<256, 256, 0, stream>>>(ws, pa.lsc, (float*)d_out);
}